// Round 6
// baseline (308.498 us; speedup 1.0000x reference)
//
#include <hip/hip_runtime.h>

typedef _Float16 h16_t;
typedef _Float16 half8 __attribute__((ext_vector_type(8)));
typedef _Float16 half4v __attribute__((ext_vector_type(4)));
typedef float f32x4 __attribute__((ext_vector_type(4)));

#define SEQ 2048
#define DM 2048
#define NHEAD 16
#define HDIM 128
#define QKVW 6144

#define GLOAD_LDS(g, l)                                                   \
  __builtin_amdgcn_global_load_lds(                                       \
      (const __attribute__((address_space(1))) void*)(g),                 \
      (__attribute__((address_space(3))) void*)(l), 16, 0, 0)

#define VMCNT0 asm volatile("s_waitcnt vmcnt(0)" ::: "memory")
#define VMCNT6 asm volatile("s_waitcnt vmcnt(6)" ::: "memory")

// ---------------- fp32 -> (hi,lo) fp16 split ----------------
__global__ void cvt_split(const float* __restrict__ src, h16_t* __restrict__ hi,
                          h16_t* __restrict__ lo, int n4) {
  int i = blockIdx.x * blockDim.x + threadIdx.x;
  if (i < n4) {
    float4 v = reinterpret_cast<const float4*>(src)[i];
    half4v h, l;
    float x;
    x = v.x; h[0] = (h16_t)x; l[0] = (h16_t)(x - (float)h[0]);
    x = v.y; h[1] = (h16_t)x; l[1] = (h16_t)(x - (float)h[1]);
    x = v.z; h[2] = (h16_t)x; l[2] = (h16_t)(x - (float)h[2]);
    x = v.w; h[3] = (h16_t)x; l[3] = (h16_t)(x - (float)h[3]);
    reinterpret_cast<half4v*>(hi)[i] = h;
    reinterpret_cast<half4v*>(lo)[i] = l;
  }
}

// ---------------- fp32 W[K][N] -> fp16 Wt[N][K] hi (+ lo for n < Nlo) -------
__global__ void transpose_split(const float* __restrict__ W, h16_t* __restrict__ Wt_hi,
                                h16_t* __restrict__ Wt_lo, int K, int N, int Nlo) {
  __shared__ float tile[32][33];
  int n0 = blockIdx.x * 32, k0 = blockIdx.y * 32;
  int tx = threadIdx.x, ty = threadIdx.y;  // 32 x 8
#pragma unroll
  for (int j = 0; j < 4; ++j)
    tile[ty + 8 * j][tx] = W[(size_t)(k0 + ty + 8 * j) * N + n0 + tx];
  __syncthreads();
  bool do_lo = (Wt_lo != nullptr) && (n0 < Nlo);
#pragma unroll
  for (int j = 0; j < 4; ++j) {
    float v = tile[tx][ty + 8 * j];
    h16_t hv = (h16_t)v;
    size_t off = (size_t)(n0 + ty + 8 * j) * K + k0 + tx;
    Wt_hi[off] = hv;
    if (do_lo) Wt_lo[off] = (h16_t)(v - (float)hv);
  }
}

// ---------------- fp16 V columns of qkv -> Vt[vc][s] ----------------
__global__ void vtrans_kernel(const h16_t* __restrict__ qkv_hi, h16_t* __restrict__ vt) {
  __shared__ h16_t tile[32][33];
  int vc0 = blockIdx.x * 32, s0 = blockIdx.y * 32;
  int tx = threadIdx.x, ty = threadIdx.y;  // 32 x 8
#pragma unroll
  for (int j = 0; j < 4; ++j)
    tile[ty + 8 * j][tx] = qkv_hi[(size_t)(s0 + ty + 8 * j) * QKVW + 4096 + vc0 + tx];
  __syncthreads();
#pragma unroll
  for (int j = 0; j < 4; ++j)
    vt[(size_t)(vc0 + ty + 8 * j) * SEQ + s0 + tx] = tile[tx][ty + 8 * j];
}

// ---------------- GEMM body: C[M][N] = A[M][K]*Bt[N][K]^T + bias -----------
// 128x128 tile, BK=32, 4 waves (2x2). Double-buffered global_load_lds with
// the corrected pipeline: VMCNT0 (stage(i), issued one compute-phase ago) ->
// raw s_barrier (no compiler drain) -> issue stage(i+1) -> MFMA (setprio).
// SPLIT: 3-product Markidis. OUT: 0 = fp16 hi, 1 = fp16 hi+lo, 2 = fp32.
template <int SPLIT, int OUT>
__device__ __forceinline__ void gemm_body(
    char* smem,
    const h16_t* __restrict__ Ahi, const h16_t* __restrict__ Alo,
    const h16_t* __restrict__ Bhi, const h16_t* __restrict__ Blo,
    const float* __restrict__ bias, void* __restrict__ Cout,
    h16_t* __restrict__ Clo, int brow, int bcol, int ldc, int K, int ldlo,
    int tid) {
  constexpr int BUF = SPLIT ? 32768 : 16384;
  const int w = tid >> 6, lane = tid & 63, c = lane & 15, g = lane >> 4;
  const int wr = (w >> 1) * 64, wc = (w & 1) * 64;

  f32x4 acc[4][4] = {};

  // stage K-step k0 into buffer bufi (linear dest, inverse-swizzled source)
  auto stage = [&](int bufi, int k0) {
    char* buf = smem + bufi * BUF;
#pragma unroll
    for (int it = 0; it < 2; ++it) {
      int B = it * 256 + tid;
      int row = B >> 2;
      int c8 = (B & 3) ^ ((row >> 1) & 3);
      int loff = it * 4096 + w * 1024;
      GLOAD_LDS(Ahi + (size_t)(brow + row) * K + k0 + c8 * 8, buf + loff);
      GLOAD_LDS(Bhi + (size_t)(bcol + row) * K + k0 + c8 * 8, buf + 8192 + loff);
      if (SPLIT) {
        GLOAD_LDS(Alo + (size_t)(brow + row) * K + k0 + c8 * 8, buf + 16384 + loff);
        GLOAD_LDS(Blo + (size_t)(bcol + row) * K + k0 + c8 * 8, buf + 24576 + loff);
      }
    }
  };

  int cur = 0;
  stage(0, 0);

#pragma unroll 1
  for (int k0 = 0; k0 < K; k0 += 32) {
    VMCNT0;                             // own stage(i) landed (issued 1 phase ago)
    __builtin_amdgcn_s_barrier();       // everyone's stage(i) landed + prev reads done
    __builtin_amdgcn_sched_barrier(0);
    if (k0 + 32 < K) stage(cur ^ 1, k0 + 32);
    __builtin_amdgcn_sched_barrier(0);

    const char* bufc = smem + cur * BUF;
    half8 afh[4], bfh[4], afl[4], bfl[4];
#pragma unroll
    for (int f = 0; f < 4; ++f) {
      int rowa = wr + f * 16 + c;
      int offa = rowa * 64 + ((g ^ ((rowa >> 1) & 3)) * 16);
      int rowb = wc + f * 16 + c;
      int offb = rowb * 64 + ((g ^ ((rowb >> 1) & 3)) * 16);
      afh[f] = *reinterpret_cast<const half8*>(bufc + offa);
      bfh[f] = *reinterpret_cast<const half8*>(bufc + 8192 + offb);
      if (SPLIT) {
        afl[f] = *reinterpret_cast<const half8*>(bufc + 16384 + offa);
        bfl[f] = *reinterpret_cast<const half8*>(bufc + 24576 + offb);
      }
    }
    __builtin_amdgcn_s_setprio(1);
#pragma unroll
    for (int fm = 0; fm < 4; ++fm)
#pragma unroll
      for (int fn = 0; fn < 4; ++fn) {
        acc[fm][fn] = __builtin_amdgcn_mfma_f32_16x16x32_f16(afh[fm], bfh[fn], acc[fm][fn], 0, 0, 0);
        if (SPLIT) {
          acc[fm][fn] = __builtin_amdgcn_mfma_f32_16x16x32_f16(afh[fm], bfl[fn], acc[fm][fn], 0, 0, 0);
          acc[fm][fn] = __builtin_amdgcn_mfma_f32_16x16x32_f16(afl[fm], bfh[fn], acc[fm][fn], 0, 0, 0);
        }
      }
    __builtin_amdgcn_s_setprio(0);
    cur ^= 1;
  }

#pragma unroll
  for (int fm = 0; fm < 4; ++fm)
#pragma unroll
    for (int fn = 0; fn < 4; ++fn) {
      int col = bcol + wc + fn * 16 + c;
      float bv = bias[col];
#pragma unroll
      for (int r = 0; r < 4; ++r) {
        int row = brow + wr + fm * 16 + 4 * g + r;
        float v = acc[fm][fn][r] + bv;
        if (OUT == 2) {
          ((float*)Cout)[(size_t)row * ldc + col] = v;
        } else {
          h16_t hv = (h16_t)v;
          ((h16_t*)Cout)[(size_t)row * ldc + col] = hv;
          if (OUT == 1) Clo[(size_t)row * ldlo + col] = (h16_t)(v - (float)hv);
        }
      }
    }
}

// ---------------- merged QKV GEMM: split q,k cols + single-product v cols ---
__global__ __launch_bounds__(256) void gemm_qkv(
    const h16_t* __restrict__ h_hi, const h16_t* __restrict__ h_lo,
    const h16_t* __restrict__ qkvT_hi, const h16_t* __restrict__ qkvT_lo,
    const float* __restrict__ bqkv, h16_t* __restrict__ qkv_hi,
    h16_t* __restrict__ qkv_lo) {
  __shared__ __align__(16) char smem[65536];
  const int bx = blockIdx.x, by = blockIdx.y, tid = threadIdx.x;
  if (bx < 32) {
    gemm_body<1, 1>(smem, h_hi, h_lo, qkvT_hi, qkvT_lo, bqkv, qkv_hi, qkv_lo,
                    by * 128, bx * 128, QKVW, DM, 4096, tid);
  } else {
    gemm_body<0, 0>(smem, h_hi, nullptr, qkvT_hi + (size_t)4096 * DM, nullptr,
                    bqkv + 4096, qkv_hi + 4096, nullptr,
                    by * 128, (bx - 32) * 128, QKVW, DM, 0, tid);
  }
}

// ---------------- out-projection GEMM (fp32 out) ----------------
__global__ __launch_bounds__(256) void gemm_oproj(
    const h16_t* __restrict__ A, const h16_t* __restrict__ Bt,
    const float* __restrict__ bias, float* __restrict__ Cout) {
  __shared__ __align__(16) char smem[32768];
  gemm_body<0, 2>(smem, A, nullptr, Bt, nullptr, bias, Cout, nullptr,
                  blockIdx.y * 128, blockIdx.x * 128, DM, DM, 0, threadIdx.x);
}

// ---------------- cos/sin table [SEQ][64] fp32 ----------------
__global__ void ctab_kernel(float2* __restrict__ tab) {
  int idx = blockIdx.x * blockDim.x + threadIdx.x;  // 2048*64
  int s = idx >> 6, i = idx & 63;
  float freq = 1.0f / powf(10000.0f, (float)(2 * i) / 128.0f);
  float ang = (float)s * freq;
  float sn, cs;
  sincosf(ang, &sn, &cs);
  tab[idx] = make_float2(cs, sn);
}

// ---------------- RoPE (interleaved pairs), in-place on split q,k ----------
// Folds the reference's *sqrt(128) logit scale into q (exact fp32, commutes
// with the rotation).
__global__ void rope_kernel(h16_t* __restrict__ hi, h16_t* __restrict__ lo,
                            const float2* __restrict__ tab) {
  int idx = blockIdx.x * blockDim.x + threadIdx.x;  // 2048*2*16*64
  int i = idx & 63;
  int hh = (idx >> 6) & 15;
  int part = (idx >> 10) & 1;
  int s = idx >> 11;
  float2 cc = tab[s * 64 + i];
  float fac = part ? 1.0f : 11.31370849898476f;  // sqrt(128) folded into q
  size_t offh = (size_t)s * QKVW + part * 2048 + hh * 128 + 2 * i;
  size_t offl = (size_t)s * 4096 + part * 2048 + hh * 128 + 2 * i;
  float x0 = (float)hi[offh] + (float)lo[offl];
  float x1 = (float)hi[offh + 1] + (float)lo[offl + 1];
  float y0 = (x0 * cc.x - x1 * cc.y) * fac;
  float y1 = (x0 * cc.y + x1 * cc.x) * fac;
  h16_t h0 = (h16_t)y0, h1 = (h16_t)y1;
  hi[offh] = h0;     lo[offl] = (h16_t)(y0 - (float)h0);
  hi[offh + 1] = h1; lo[offl + 1] = (h16_t)(y1 - (float)h1);
}

// ---------------- causal flash attention, split-K + counted-vmcnt ----------
// 768 blocks: h = p&15 (XCD-pinned), cq = p>>4:
//   cq<16 : qb=16+cq, keys [0,1024)            -> partial chunk 0
//   cq<32 : qb=47-cq, keys [1024,(qb+1)*64)    -> partial chunk 1
//   else  : qb=47-cq (15..0), all keys         -> direct ctx write
// 3-buffer pipeline, ONE raw s_barrier per tile, counted vmcnt(6): stage(t)
// issued 2 tiles ahead of use -> L2 latency hidden (no vmcnt(0) drain).
__global__ __launch_bounds__(256) void attn_kernel(const h16_t* __restrict__ qhi,
                                                   const h16_t* __restrict__ qlo,
                                                   const h16_t* __restrict__ vt,
                                                   h16_t* __restrict__ ctx,
                                                   float* __restrict__ Opart,
                                                   float* __restrict__ ms) {
  __shared__ __align__(16) char smem[3 * 24576];
  const int tid = threadIdx.x, w = tid >> 6, lane = tid & 63, c = lane & 15, g = lane >> 4;
  const int p = blockIdx.x;
  const int h = p & 15;
  const int cq = p >> 4;
  int qb, t0, nt, pidx;
  if (cq < 16)      { qb = 16 + cq; t0 = 0;  nt = 32;          pidx = h * 32 + cq * 2; }
  else if (cq < 32) { qb = 47 - cq; t0 = 32; nt = 2 * qb - 30; pidx = h * 32 + (qb - 16) * 2 + 1; }
  else              { qb = 47 - cq; t0 = 0;  nt = 2 * qb + 2;  pidx = -1; }

  const h16_t* Kph = qhi + 2048 + h * HDIM;
  const h16_t* Kpl = qlo + 2048 + h * HDIM;
  const h16_t* Vth = vt + (size_t)h * HDIM * SEQ;
  const float L2E = 1.4426950408889634f;

  const int q0 = qb * 64;
  const int qw = q0 + w * 16;

  // stage one KVBLK=32 tile (Khi, Klo row-major swizzled; Vt [128 d][32 key])
  auto stage = [&](int bufi, int t) {
    char* buf = smem + bufi * 24576;
    const int k0 = t * 32;
#pragma unroll
    for (int it = 0; it < 2; ++it) {
      int B = it * 256 + tid;
      int loff = it * 4096 + w * 1024;
      int row = B >> 4;                       // key row 0..31
      int c16 = (B & 15) ^ (row & 7);
      GLOAD_LDS(Kph + (size_t)(k0 + row) * QKVW + c16 * 8, buf + loff);
      GLOAD_LDS(Kpl + (size_t)(k0 + row) * 4096 + c16 * 8, buf + 8192 + loff);
      int rv = B >> 2;                        // d row 0..127
      int c4 = (B & 3) ^ ((rv >> 1) & 3);
      GLOAD_LDS(Vth + (size_t)rv * SEQ + k0 + c4 * 8, buf + 16384 + loff);
    }
  };

  half8 qfh[4], qfl[4];
#pragma unroll
  for (int kc = 0; kc < 4; ++kc) {
    qfh[kc] = *reinterpret_cast<const half8*>(qhi + (size_t)(qw + c) * QKVW + h * HDIM + kc * 32 + g * 8);
    qfl[kc] = *reinterpret_cast<const half8*>(qlo + (size_t)(qw + c) * 4096 + h * HDIM + kc * 32 + g * 8);
  }

  f32x4 oacc[8] = {};
  float m_run = -3.0e38f, s_run = 0.f;

  stage(0, t0);
  if (nt > 1) stage(1, t0 + 1);

#pragma unroll 1
  for (int i = 0; i < nt; ++i) {
    // wait own stage(i) loads complete (6 loads of stage(i+1) may remain),
    // then raw barrier (NO compiler vmcnt(0) drain), then pin ordering.
    if (i + 1 < nt) { VMCNT6; } else { VMCNT0; }
    __builtin_amdgcn_s_barrier();
    __builtin_amdgcn_sched_barrier(0);
    if (i + 2 < nt) stage((i + 2) % 3, t0 + i + 2);

    const int k0 = (t0 + i) * 32;
    const char* buf = smem + (i % 3) * 24576;
    const char* bufV = buf + 16384;

    // S^T = K * Q, 3-product split (32 keys x 16 q per wave)
    f32x4 st[2] = {};
    __builtin_amdgcn_s_setprio(1);
#pragma unroll
    for (int kc = 0; kc < 4; ++kc)
#pragma unroll
      for (int fm = 0; fm < 2; ++fm) {
        int row = fm * 16 + c;
        int so = row * 256 + (((4 * kc + g) ^ (row & 7)) * 16);
        half8 kfh = *reinterpret_cast<const half8*>(buf + so);
        half8 kfl = *reinterpret_cast<const half8*>(buf + 8192 + so);
        st[fm] = __builtin_amdgcn_mfma_f32_16x16x32_f16(kfh, qfh[kc], st[fm], 0, 0, 0);
        st[fm] = __builtin_amdgcn_mfma_f32_16x16x32_f16(kfh, qfl[kc], st[fm], 0, 0, 0);
        st[fm] = __builtin_amdgcn_mfma_f32_16x16x32_f16(kfl, qfh[kc], st[fm], 0, 0, 0);
      }
    __builtin_amdgcn_s_setprio(0);

    // causal mask + online softmax (defer-max, THR=8; scale pre-folded into q)
    float p_[2][4];
    float tmax = -3.0e38f;
    const int qg = qw + c;
#pragma unroll
    for (int fm = 0; fm < 2; ++fm)
#pragma unroll
      for (int r = 0; r < 4; ++r) {
        float sf = st[fm][r];
        int key = k0 + fm * 16 + 4 * g + r;
        sf = (key > qg) ? -3.0e38f : sf;
        p_[fm][r] = sf;
        tmax = fmaxf(tmax, sf);
      }
    tmax = fmaxf(tmax, __shfl_xor(tmax, 16));
    tmax = fmaxf(tmax, __shfl_xor(tmax, 32));
    if (!__all(tmax - m_run <= 8.0f)) {
      float m_new = fmaxf(m_run, tmax);
      float alpha = exp2f((m_run - m_new) * L2E);
      float ar[4];
#pragma unroll
      for (int r = 0; r < 4; ++r) ar[r] = __shfl(alpha, 4 * g + r);
#pragma unroll
      for (int tt = 0; tt < 8; ++tt)
#pragma unroll
        for (int r = 0; r < 4; ++r) oacc[tt][r] *= ar[r];
      s_run *= alpha;
      m_run = m_new;
    }
    float rs = 0.f;
#pragma unroll
    for (int fm = 0; fm < 2; ++fm)
#pragma unroll
      for (int r = 0; r < 4; ++r) {
        float e = exp2f((p_[fm][r] - m_run) * L2E);
        p_[fm][r] = e;
        rs += e;
      }
    rs += __shfl_xor(rs, 16);
    rs += __shfl_xor(rs, 32);
    s_run += rs;

    // pack P fragment: slot i <-> key 16*(i>>2) + 4g + (i&3)  (per-lane, free)
    half8 ap;
#pragma unroll
    for (int j = 0; j < 8; ++j) ap[j] = (h16_t)p_[j >> 2][j & 3];

    // PV: B-frag = two swizzled b64 reads of Vt (keys 4g..4g+3, 16+4g..16+4g+3)
    __builtin_amdgcn_s_setprio(1);
#pragma unroll
    for (int tt = 0; tt < 8; ++tt) {
      int row = 16 * tt + c;
      int sw = (row >> 1) & 3;
      int b1 = (g >> 1), b2 = 2 + (g >> 1);
      int a1 = row * 64 + (((b1 ^ sw)) * 16) + 8 * (g & 1);
      int a2 = row * 64 + (((b2 ^ sw)) * 16) + 8 * (g & 1);
      union { half8 v8; half4v v4[2]; } u;
      u.v4[0] = *reinterpret_cast<const half4v*>(bufV + a1);
      u.v4[1] = *reinterpret_cast<const half4v*>(bufV + a2);
      oacc[tt] = __builtin_amdgcn_mfma_f32_16x16x32_f16(ap, u.v8, oacc[tt], 0, 0, 0);
    }
    __builtin_amdgcn_s_setprio(0);
  }

  if (pidx >= 0) {
    // partial: store fp32 O, m, s (consistent w.r.t. m_run reference point)
    float* Od = Opart + (size_t)pidx * 8192;
#pragma unroll
    for (int tt = 0; tt < 8; ++tt)
#pragma unroll
      for (int r = 0; r < 4; ++r)
        Od[(w * 16 + 4 * g + r) * 128 + tt * 16 + c] = oacc[tt][r];
    if (lane < 16) {
      ms[pidx * 128 + w * 16 + c] = m_run;
      ms[pidx * 128 + 64 + w * 16 + c] = s_run;
    }
  } else {
    float sr[4];
#pragma unroll
    for (int r = 0; r < 4; ++r) sr[r] = __shfl(s_run, 4 * g + r);
#pragma unroll
    for (int tt = 0; tt < 8; ++tt)
#pragma unroll
      for (int r = 0; r < 4; ++r) {
        float v = oacc[tt][r] / sr[r];
        ctx[(size_t)(qw + 4 * g + r) * DM + h * HDIM + tt * 16 + c] = (h16_t)v;
      }
  }
}

// ---------------- merge the 2-chunk partials (qb >= 16) ----------------
__global__ void attn_reduce(const float* __restrict__ Opart, const float* __restrict__ ms,
                            h16_t* __restrict__ ctx) {
  const float L2E = 1.4426950408889634f;
  int b = blockIdx.x;          // 256 = 16 heads x 16 qb
  int h = b & 15, qi = b >> 4; // qb = 16 + qi
  int p0 = (h * 32 + qi * 2);
  int tid = threadIdx.x;
  int row = tid >> 2, seg = (tid & 3) * 32;
  float m1 = ms[p0 * 128 + row], s1 = ms[p0 * 128 + 64 + row];
  float m2 = ms[(p0 + 1) * 128 + row], s2 = ms[(p0 + 1) * 128 + 64 + row];
  float M = fmaxf(m1, m2);
  float w1 = exp2f((m1 - M) * L2E), w2 = exp2f((m2 - M) * L2E);
  float inv = 1.0f / (s1 * w1 + s2 * w2);
  const float* O1 = Opart + (size_t)p0 * 8192 + row * 128 + seg;
  const float* O2 = O1 + 8192;
  h16_t* dst = ctx + (size_t)((16 + qi) * 64 + row) * DM + h * HDIM + seg;
#pragma unroll
  for (int j = 0; j < 32; j += 4) {
    float4 a = *reinterpret_cast<const float4*>(O1 + j);
    float4 c2 = *reinterpret_cast<const float4*>(O2 + j);
    dst[j]     = (h16_t)((a.x * w1 + c2.x * w2) * inv);
    dst[j + 1] = (h16_t)((a.y * w1 + c2.y * w2) * inv);
    dst[j + 2] = (h16_t)((a.z * w1 + c2.z * w2) * inv);
    dst[j + 3] = (h16_t)((a.w * w1 + c2.w * w2) * inv);
  }
}

extern "C" void kernel_launch(void* const* d_in, const int* in_sizes, int n_in,
                              void* d_out, int out_size, void* d_ws, size_t ws_size,
                              hipStream_t stream) {
  const float* hs   = (const float*)d_in[0];
  const float* wqkv = (const float*)d_in[1];
  const float* bqkv = (const float*)d_in[2];
  const float* wo   = (const float*)d_in[3];
  const float* bo   = (const float*)d_in[4];
  float* out = (float*)d_out;

  char* ws = (char*)d_ws;
  const size_t MB = 1u << 20;
  h16_t* h_hi    = (h16_t*)(ws + 0 * MB);    // 8 MB  (reused as ctx16 later)
  h16_t* h_lo    = (h16_t*)(ws + 8 * MB);    // 8 MB
  h16_t* qkvT_hi = (h16_t*)(ws + 16 * MB);   // 24 MB [6144][2048]
  h16_t* qkvT_lo = (h16_t*)(ws + 40 * MB);   // 16 MB [4096][2048]
  h16_t* woT     = (h16_t*)(ws + 56 * MB);   // 8 MB  [2048][2048]
  h16_t* qkv_hi  = (h16_t*)(ws + 64 * MB);   // 24 MB [2048][6144]
  h16_t* qkv_lo  = (h16_t*)(ws + 88 * MB);   // 16 MB [2048][4096]
  float2* ctab   = (float2*)(ws + 104 * MB); // 1 MB  [2048][64]
  h16_t* vt      = (h16_t*)(ws + 105 * MB);  // 8 MB  [2048 vc][2048 s]
  // attn partials reuse the weight-transpose region (consumed before attn):
  float* Opart   = (float*)(ws + 16 * MB);   // 16 MB [512][64][128] fp32
  float* msbuf   = (float*)(ws + 32 * MB);   // 256 KB [512][2][64] fp32
  h16_t* ctx16   = h_hi;

  cvt_split<<<(SEQ * DM / 4 + 255) / 256, 256, 0, stream>>>(hs, h_hi, h_lo, SEQ * DM / 4);
  transpose_split<<<dim3(QKVW / 32, DM / 32), dim3(32, 8), 0, stream>>>(
      wqkv, qkvT_hi, qkvT_lo, DM, QKVW, 4096);
  transpose_split<<<dim3(DM / 32, DM / 32), dim3(32, 8), 0, stream>>>(
      wo, woT, nullptr, DM, DM, 0);
  ctab_kernel<<<(SEQ * 64) / 256, 256, 0, stream>>>(ctab);

  // merged QKV GEMM: x<32 -> split q,k cols (3-product, hi+lo out);
  //                  x>=32 -> v cols (single product, hi out)
  gemm_qkv<<<dim3(48, 16), 256, 0, stream>>>(
      h_hi, h_lo, qkvT_hi, qkvT_lo, bqkv, qkv_hi, qkv_lo);

  vtrans_kernel<<<dim3(DM / 32, SEQ / 32), dim3(32, 8), 0, stream>>>(qkv_hi, vt);
  rope_kernel<<<(SEQ * 2 * NHEAD * 64) / 256, 256, 0, stream>>>(qkv_hi, qkv_lo, ctab);

  attn_kernel<<<768, 256, 0, stream>>>(qkv_hi, qkv_lo, vt, ctx16, Opart, msbuf);
  attn_reduce<<<256, 256, 0, stream>>>(Opart, msbuf, ctx16);

  gemm_oproj<<<dim3(DM / 128, SEQ / 128), 256, 0, stream>>>(ctx16, woT, bo, out);
}

// Round 7
// 296.305 us; speedup vs baseline: 1.0411x; 1.0411x over previous
//
#include <hip/hip_runtime.h>

typedef _Float16 h16_t;
typedef _Float16 half8 __attribute__((ext_vector_type(8)));
typedef _Float16 half4v __attribute__((ext_vector_type(4)));
typedef float f32x4 __attribute__((ext_vector_type(4)));

#define SEQ 2048
#define DM 2048
#define NHEAD 16
#define HDIM 128
#define QKVW 6144

#define GLOAD_LDS(g, l)                                                   \
  __builtin_amdgcn_global_load_lds(                                       \
      (const __attribute__((address_space(1))) void*)(g),                 \
      (__attribute__((address_space(3))) void*)(l), 16, 0, 0)

#define VMCNT(n) asm volatile("s_waitcnt vmcnt(" #n ")" ::: "memory")
#define LGKMCNT0 asm volatile("s_waitcnt lgkmcnt(0)" ::: "memory")

// ---------------- fp32 -> (hi,lo) fp16 split ----------------
__global__ void cvt_split(const float* __restrict__ src, h16_t* __restrict__ hi,
                          h16_t* __restrict__ lo, int n4) {
  int i = blockIdx.x * blockDim.x + threadIdx.x;
  if (i < n4) {
    float4 v = reinterpret_cast<const float4*>(src)[i];
    half4v h, l;
    float x;
    x = v.x; h[0] = (h16_t)x; l[0] = (h16_t)(x - (float)h[0]);
    x = v.y; h[1] = (h16_t)x; l[1] = (h16_t)(x - (float)h[1]);
    x = v.z; h[2] = (h16_t)x; l[2] = (h16_t)(x - (float)h[2]);
    x = v.w; h[3] = (h16_t)x; l[3] = (h16_t)(x - (float)h[3]);
    reinterpret_cast<half4v*>(hi)[i] = h;
    reinterpret_cast<half4v*>(lo)[i] = l;
  }
}

// ---------------- fp32 W[K][N] -> fp16 Wt[N][K] hi (+ lo for n < Nlo) -------
__global__ void transpose_split(const float* __restrict__ W, h16_t* __restrict__ Wt_hi,
                                h16_t* __restrict__ Wt_lo, int K, int N, int Nlo) {
  __shared__ float tile[32][33];
  int n0 = blockIdx.x * 32, k0 = blockIdx.y * 32;
  int tx = threadIdx.x, ty = threadIdx.y;  // 32 x 8
#pragma unroll
  for (int j = 0; j < 4; ++j)
    tile[ty + 8 * j][tx] = W[(size_t)(k0 + ty + 8 * j) * N + n0 + tx];
  __syncthreads();
  bool do_lo = (Wt_lo != nullptr) && (n0 < Nlo);
#pragma unroll
  for (int j = 0; j < 4; ++j) {
    float v = tile[tx][ty + 8 * j];
    h16_t hv = (h16_t)v;
    size_t off = (size_t)(n0 + ty + 8 * j) * K + k0 + tx;
    Wt_hi[off] = hv;
    if (do_lo) Wt_lo[off] = (h16_t)(v - (float)hv);
  }
}

// ---------------- fp16 V columns of qkv -> Vt[vc][s] ----------------
__global__ void vtrans_kernel(const h16_t* __restrict__ qkv_hi, h16_t* __restrict__ vt) {
  __shared__ h16_t tile[32][33];
  int vc0 = blockIdx.x * 32, s0 = blockIdx.y * 32;
  int tx = threadIdx.x, ty = threadIdx.y;  // 32 x 8
#pragma unroll
  for (int j = 0; j < 4; ++j)
    tile[ty + 8 * j][tx] = qkv_hi[(size_t)(s0 + ty + 8 * j) * QKVW + 4096 + vc0 + tx];
  __syncthreads();
#pragma unroll
  for (int j = 0; j < 4; ++j)
    vt[(size_t)(vc0 + ty + 8 * j) * SEQ + s0 + tx] = tile[tx][ty + 8 * j];
}

// ---------------- GEMM body: C[M][N] = A[M][K]*Bt[N][K]^T + bias -----------
// 128x128 tile, BK=32, 4 waves (2x2). Counted-vmcnt pipeline (never drain-0
// in the loop):
//  SPLIT (2 x 32KB bufs): vmcnt(8) | barrier | ds_reads | lgkmcnt(0) |
//    barrier2 | stage(i+2 -> cur buf) | MFMA.  (WAR via barrier2.)
//  plain (3 x 16KB bufs): vmcnt(4) | barrier | stage(i+2 -> (i+2)%3) |
//    ds_reads | MFMA.  (3rd buffer removes the WAR barrier entirely.)
// SPLIT: 3-product Markidis. OUT: 0 = fp16 hi, 1 = fp16 hi+lo, 2 = fp32.
template <int SPLIT, int OUT>
__device__ __forceinline__ void gemm_body(
    char* smem,
    const h16_t* __restrict__ Ahi, const h16_t* __restrict__ Alo,
    const h16_t* __restrict__ Bhi, const h16_t* __restrict__ Blo,
    const float* __restrict__ bias, void* __restrict__ Cout,
    h16_t* __restrict__ Clo, int brow, int bcol, int ldc, int K, int ldlo,
    int tid) {
  constexpr int BUF = SPLIT ? 32768 : 16384;
  constexpr int NBUF = SPLIT ? 2 : 3;
  const int w = tid >> 6, lane = tid & 63, c = lane & 15, g = lane >> 4;
  const int wr = (w >> 1) * 64, wc = (w & 1) * 64;

  f32x4 acc[4][4] = {};

  // stage K-step k0 into buffer bufi (linear dest, inverse-swizzled source)
  auto stage = [&](int bufi, int k0) {
    char* buf = smem + bufi * BUF;
#pragma unroll
    for (int it = 0; it < 2; ++it) {
      int B = it * 256 + tid;
      int row = B >> 2;
      int c8 = (B & 3) ^ ((row >> 1) & 3);
      int loff = it * 4096 + w * 1024;
      GLOAD_LDS(Ahi + (size_t)(brow + row) * K + k0 + c8 * 8, buf + loff);
      GLOAD_LDS(Bhi + (size_t)(bcol + row) * K + k0 + c8 * 8, buf + 8192 + loff);
      if (SPLIT) {
        GLOAD_LDS(Alo + (size_t)(brow + row) * K + k0 + c8 * 8, buf + 16384 + loff);
        GLOAD_LDS(Blo + (size_t)(bcol + row) * K + k0 + c8 * 8, buf + 24576 + loff);
      }
    }
  };

  const int nsteps = K / 32;
  stage(0, 0);
  stage(1, 32);

#pragma unroll 1
  for (int i = 0; i < nsteps; ++i) {
    const int k0 = i * 32;
    // stage(i) landed; stage(i+1)'s loads (8 split / 4 plain) stay in flight
    if (i + 1 < nsteps) {
      if (SPLIT) { VMCNT(8); } else { VMCNT(4); }
    } else {
      VMCNT(0);
    }
    __builtin_amdgcn_s_barrier();
    __builtin_amdgcn_sched_barrier(0);

    if (!SPLIT) {
      // 3-buf: (i+2)%3's readers (tile i-1) completed before this barrier
      if (i + 2 < nsteps) stage((i + 2) % 3, k0 + 64);
      __builtin_amdgcn_sched_barrier(0);
    }

    const char* bufc = smem + (i % NBUF) * BUF;
    half8 afh[4], bfh[4], afl[4], bfl[4];
#pragma unroll
    for (int f = 0; f < 4; ++f) {
      int rowa = wr + f * 16 + c;
      int offa = rowa * 64 + ((g ^ ((rowa >> 1) & 3)) * 16);
      int rowb = wc + f * 16 + c;
      int offb = rowb * 64 + ((g ^ ((rowb >> 1) & 3)) * 16);
      afh[f] = *reinterpret_cast<const half8*>(bufc + offa);
      bfh[f] = *reinterpret_cast<const half8*>(bufc + 8192 + offb);
      if (SPLIT) {
        afl[f] = *reinterpret_cast<const half8*>(bufc + 16384 + offa);
        bfl[f] = *reinterpret_cast<const half8*>(bufc + 24576 + offb);
      }
    }

    if (SPLIT) {
      LGKMCNT0;                         // my reads of cur are complete
      __builtin_amdgcn_sched_barrier(0);
      __builtin_amdgcn_s_barrier();     // all waves done reading cur
      __builtin_amdgcn_sched_barrier(0);
      if (i + 2 < nsteps) stage(i % 2, k0 + 64);  // overwrite cur for i+2
      __builtin_amdgcn_sched_barrier(0);
    }

    __builtin_amdgcn_s_setprio(1);
#pragma unroll
    for (int fm = 0; fm < 4; ++fm)
#pragma unroll
      for (int fn = 0; fn < 4; ++fn) {
        acc[fm][fn] = __builtin_amdgcn_mfma_f32_16x16x32_f16(afh[fm], bfh[fn], acc[fm][fn], 0, 0, 0);
        if (SPLIT) {
          acc[fm][fn] = __builtin_amdgcn_mfma_f32_16x16x32_f16(afh[fm], bfl[fn], acc[fm][fn], 0, 0, 0);
          acc[fm][fn] = __builtin_amdgcn_mfma_f32_16x16x32_f16(afl[fm], bfh[fn], acc[fm][fn], 0, 0, 0);
        }
      }
    __builtin_amdgcn_s_setprio(0);
  }

#pragma unroll
  for (int fm = 0; fm < 4; ++fm)
#pragma unroll
    for (int fn = 0; fn < 4; ++fn) {
      int col = bcol + wc + fn * 16 + c;
      float bv = bias[col];
#pragma unroll
      for (int r = 0; r < 4; ++r) {
        int row = brow + wr + fm * 16 + 4 * g + r;
        float v = acc[fm][fn][r] + bv;
        if (OUT == 2) {
          ((float*)Cout)[(size_t)row * ldc + col] = v;
        } else {
          h16_t hv = (h16_t)v;
          ((h16_t*)Cout)[(size_t)row * ldc + col] = hv;
          if (OUT == 1) Clo[(size_t)row * ldlo + col] = (h16_t)(v - (float)hv);
        }
      }
    }
}

// ---------------- q,k columns: split 3-product GEMM ----------------
__global__ __launch_bounds__(256) void gemm_qk(
    const h16_t* __restrict__ h_hi, const h16_t* __restrict__ h_lo,
    const h16_t* __restrict__ qkvT_hi, const h16_t* __restrict__ qkvT_lo,
    const float* __restrict__ bqkv, h16_t* __restrict__ qkv_hi,
    h16_t* __restrict__ qkv_lo) {
  __shared__ __align__(16) char smem[65536];
  gemm_body<1, 1>(smem, h_hi, h_lo, qkvT_hi, qkvT_lo, bqkv, qkv_hi, qkv_lo,
                  blockIdx.y * 128, blockIdx.x * 128, QKVW, DM, 4096, threadIdx.x);
}

// ---------------- v columns: plain GEMM ----------------
__global__ __launch_bounds__(256) void gemm_v(
    const h16_t* __restrict__ h_hi, const h16_t* __restrict__ qkvT_hi,
    const float* __restrict__ bqkv, h16_t* __restrict__ qkv_hi) {
  __shared__ __align__(16) char smem[49152];
  gemm_body<0, 0>(smem, h_hi, nullptr, qkvT_hi + (size_t)4096 * DM, nullptr,
                  bqkv + 4096, qkv_hi + 4096, nullptr,
                  blockIdx.y * 128, blockIdx.x * 128, QKVW, DM, 0, threadIdx.x);
}

// ---------------- out-projection GEMM (fp32 out) ----------------
__global__ __launch_bounds__(256) void gemm_oproj(
    const h16_t* __restrict__ A, const h16_t* __restrict__ Bt,
    const float* __restrict__ bias, float* __restrict__ Cout) {
  __shared__ __align__(16) char smem[49152];
  gemm_body<0, 2>(smem, A, nullptr, Bt, nullptr, bias, Cout, nullptr,
                  blockIdx.y * 128, blockIdx.x * 128, DM, DM, 0, threadIdx.x);
}

// ---------------- cos/sin table [SEQ][64] fp32 ----------------
__global__ void ctab_kernel(float2* __restrict__ tab) {
  int idx = blockIdx.x * blockDim.x + threadIdx.x;  // 2048*64
  int s = idx >> 6, i = idx & 63;
  float freq = 1.0f / powf(10000.0f, (float)(2 * i) / 128.0f);
  float ang = (float)s * freq;
  float sn, cs;
  sincosf(ang, &sn, &cs);
  tab[idx] = make_float2(cs, sn);
}

// ---------------- RoPE (interleaved pairs), in-place on split q,k ----------
// Folds the reference's *sqrt(128) logit scale into q (exact fp32, commutes
// with the rotation).
__global__ void rope_kernel(h16_t* __restrict__ hi, h16_t* __restrict__ lo,
                            const float2* __restrict__ tab) {
  int idx = blockIdx.x * blockDim.x + threadIdx.x;  // 2048*2*16*64
  int i = idx & 63;
  int hh = (idx >> 6) & 15;
  int part = (idx >> 10) & 1;
  int s = idx >> 11;
  float2 cc = tab[s * 64 + i];
  float fac = part ? 1.0f : 11.31370849898476f;  // sqrt(128) folded into q
  size_t offh = (size_t)s * QKVW + part * 2048 + hh * 128 + 2 * i;
  size_t offl = (size_t)s * 4096 + part * 2048 + hh * 128 + 2 * i;
  float x0 = (float)hi[offh] + (float)lo[offl];
  float x1 = (float)hi[offh + 1] + (float)lo[offl + 1];
  float y0 = (x0 * cc.x - x1 * cc.y) * fac;
  float y1 = (x0 * cc.y + x1 * cc.x) * fac;
  h16_t h0 = (h16_t)y0, h1 = (h16_t)y1;
  hi[offh] = h0;     lo[offl] = (h16_t)(y0 - (float)h0);
  hi[offh + 1] = h1; lo[offl + 1] = (h16_t)(y1 - (float)h1);
}

// ---------------- causal flash attention, split-K + counted-vmcnt ----------
// 768 blocks: h = p&15 (XCD-pinned), cq = p>>4:
//   cq<16 : qb=16+cq, keys [0,1024)            -> partial chunk 0
//   cq<32 : qb=47-cq, keys [1024,(qb+1)*64)    -> partial chunk 1
//   else  : qb=47-cq (15..0), all keys         -> direct ctx write
// 3-buffer pipeline, ONE raw s_barrier per tile, counted vmcnt(6): stage(t)
// issued 2 tiles ahead of use -> L2 latency hidden (no vmcnt(0) drain).
__global__ __launch_bounds__(256) void attn_kernel(const h16_t* __restrict__ qhi,
                                                   const h16_t* __restrict__ qlo,
                                                   const h16_t* __restrict__ vt,
                                                   h16_t* __restrict__ ctx,
                                                   float* __restrict__ Opart,
                                                   float* __restrict__ ms) {
  __shared__ __align__(16) char smem[3 * 24576];
  const int tid = threadIdx.x, w = tid >> 6, lane = tid & 63, c = lane & 15, g = lane >> 4;
  const int p = blockIdx.x;
  const int h = p & 15;
  const int cq = p >> 4;
  int qb, t0, nt, pidx;
  if (cq < 16)      { qb = 16 + cq; t0 = 0;  nt = 32;          pidx = h * 32 + cq * 2; }
  else if (cq < 32) { qb = 47 - cq; t0 = 32; nt = 2 * qb - 30; pidx = h * 32 + (qb - 16) * 2 + 1; }
  else              { qb = 47 - cq; t0 = 0;  nt = 2 * qb + 2;  pidx = -1; }

  const h16_t* Kph = qhi + 2048 + h * HDIM;
  const h16_t* Kpl = qlo + 2048 + h * HDIM;
  const h16_t* Vth = vt + (size_t)h * HDIM * SEQ;
  const float L2E = 1.4426950408889634f;

  const int q0 = qb * 64;
  const int qw = q0 + w * 16;

  // stage one KVBLK=32 tile (Khi, Klo row-major swizzled; Vt [128 d][32 key])
  auto stage = [&](int bufi, int t) {
    char* buf = smem + bufi * 24576;
    const int k0 = t * 32;
#pragma unroll
    for (int it = 0; it < 2; ++it) {
      int B = it * 256 + tid;
      int loff = it * 4096 + w * 1024;
      int row = B >> 4;                       // key row 0..31
      int c16 = (B & 15) ^ (row & 7);
      GLOAD_LDS(Kph + (size_t)(k0 + row) * QKVW + c16 * 8, buf + loff);
      GLOAD_LDS(Kpl + (size_t)(k0 + row) * 4096 + c16 * 8, buf + 8192 + loff);
      int rv = B >> 2;                        // d row 0..127
      int c4 = (B & 3) ^ ((rv >> 1) & 3);
      GLOAD_LDS(Vth + (size_t)rv * SEQ + k0 + c4 * 8, buf + 16384 + loff);
    }
  };

  half8 qfh[4], qfl[4];
#pragma unroll
  for (int kc = 0; kc < 4; ++kc) {
    qfh[kc] = *reinterpret_cast<const half8*>(qhi + (size_t)(qw + c) * QKVW + h * HDIM + kc * 32 + g * 8);
    qfl[kc] = *reinterpret_cast<const half8*>(qlo + (size_t)(qw + c) * 4096 + h * HDIM + kc * 32 + g * 8);
  }

  f32x4 oacc[8] = {};
  float m_run = -3.0e38f, s_run = 0.f;

  stage(0, t0);
  if (nt > 1) stage(1, t0 + 1);

#pragma unroll 1
  for (int i = 0; i < nt; ++i) {
    // wait own stage(i) loads complete (6 loads of stage(i+1) may remain),
    // then raw barrier (NO compiler vmcnt(0) drain), then pin ordering.
    if (i + 1 < nt) { VMCNT(6); } else { VMCNT(0); }
    __builtin_amdgcn_s_barrier();
    __builtin_amdgcn_sched_barrier(0);
    if (i + 2 < nt) stage((i + 2) % 3, t0 + i + 2);

    const int k0 = (t0 + i) * 32;
    const char* buf = smem + (i % 3) * 24576;
    const char* bufV = buf + 16384;

    // S^T = K * Q, 3-product split (32 keys x 16 q per wave)
    f32x4 st[2] = {};
    __builtin_amdgcn_s_setprio(1);
#pragma unroll
    for (int kc = 0; kc < 4; ++kc)
#pragma unroll
      for (int fm = 0; fm < 2; ++fm) {
        int row = fm * 16 + c;
        int so = row * 256 + (((4 * kc + g) ^ (row & 7)) * 16);
        half8 kfh = *reinterpret_cast<const half8*>(buf + so);
        half8 kfl = *reinterpret_cast<const half8*>(buf + 8192 + so);
        st[fm] = __builtin_amdgcn_mfma_f32_16x16x32_f16(kfh, qfh[kc], st[fm], 0, 0, 0);
        st[fm] = __builtin_amdgcn_mfma_f32_16x16x32_f16(kfh, qfl[kc], st[fm], 0, 0, 0);
        st[fm] = __builtin_amdgcn_mfma_f32_16x16x32_f16(kfl, qfh[kc], st[fm], 0, 0, 0);
      }
    __builtin_amdgcn_s_setprio(0);

    // causal mask + online softmax (defer-max, THR=8; scale pre-folded into q)
    float p_[2][4];
    float tmax = -3.0e38f;
    const int qg = qw + c;
#pragma unroll
    for (int fm = 0; fm < 2; ++fm)
#pragma unroll
      for (int r = 0; r < 4; ++r) {
        float sf = st[fm][r];
        int key = k0 + fm * 16 + 4 * g + r;
        sf = (key > qg) ? -3.0e38f : sf;
        p_[fm][r] = sf;
        tmax = fmaxf(tmax, sf);
      }
    tmax = fmaxf(tmax, __shfl_xor(tmax, 16));
    tmax = fmaxf(tmax, __shfl_xor(tmax, 32));
    if (!__all(tmax - m_run <= 8.0f)) {
      float m_new = fmaxf(m_run, tmax);
      float alpha = exp2f((m_run - m_new) * L2E);
      float ar[4];
#pragma unroll
      for (int r = 0; r < 4; ++r) ar[r] = __shfl(alpha, 4 * g + r);
#pragma unroll
      for (int tt = 0; tt < 8; ++tt)
#pragma unroll
        for (int r = 0; r < 4; ++r) oacc[tt][r] *= ar[r];
      s_run *= alpha;
      m_run = m_new;
    }
    float rs = 0.f;
#pragma unroll
    for (int fm = 0; fm < 2; ++fm)
#pragma unroll
      for (int r = 0; r < 4; ++r) {
        float e = exp2f((p_[fm][r] - m_run) * L2E);
        p_[fm][r] = e;
        rs += e;
      }
    rs += __shfl_xor(rs, 16);
    rs += __shfl_xor(rs, 32);
    s_run += rs;

    // pack P fragment: slot i <-> key 16*(i>>2) + 4g + (i&3)  (per-lane, free)
    half8 ap;
#pragma unroll
    for (int j = 0; j < 8; ++j) ap[j] = (h16_t)p_[j >> 2][j & 3];

    // PV: B-frag = two swizzled b64 reads of Vt (keys 4g..4g+3, 16+4g..16+4g+3)
    __builtin_amdgcn_s_setprio(1);
#pragma unroll
    for (int tt = 0; tt < 8; ++tt) {
      int row = 16 * tt + c;
      int sw = (row >> 1) & 3;
      int b1 = (g >> 1), b2 = 2 + (g >> 1);
      int a1 = row * 64 + (((b1 ^ sw)) * 16) + 8 * (g & 1);
      int a2 = row * 64 + (((b2 ^ sw)) * 16) + 8 * (g & 1);
      union { half8 v8; half4v v4[2]; } u;
      u.v4[0] = *reinterpret_cast<const half4v*>(bufV + a1);
      u.v4[1] = *reinterpret_cast<const half4v*>(bufV + a2);
      oacc[tt] = __builtin_amdgcn_mfma_f32_16x16x32_f16(ap, u.v8, oacc[tt], 0, 0, 0);
    }
    __builtin_amdgcn_s_setprio(0);
  }

  if (pidx >= 0) {
    // partial: store fp32 O, m, s (consistent w.r.t. m_run reference point)
    float* Od = Opart + (size_t)pidx * 8192;
#pragma unroll
    for (int tt = 0; tt < 8; ++tt)
#pragma unroll
      for (int r = 0; r < 4; ++r)
        Od[(w * 16 + 4 * g + r) * 128 + tt * 16 + c] = oacc[tt][r];
    if (lane < 16) {
      ms[pidx * 128 + w * 16 + c] = m_run;
      ms[pidx * 128 + 64 + w * 16 + c] = s_run;
    }
  } else {
    float sr[4];
#pragma unroll
    for (int r = 0; r < 4; ++r) sr[r] = __shfl(s_run, 4 * g + r);
#pragma unroll
    for (int tt = 0; tt < 8; ++tt)
#pragma unroll
      for (int r = 0; r < 4; ++r) {
        float v = oacc[tt][r] / sr[r];
        ctx[(size_t)(qw + 4 * g + r) * DM + h * HDIM + tt * 16 + c] = (h16_t)v;
      }
  }
}

// ---------------- merge the 2-chunk partials (qb >= 16) ----------------
__global__ void attn_reduce(const float* __restrict__ Opart, const float* __restrict__ ms,
                            h16_t* __restrict__ ctx) {
  const float L2E = 1.4426950408889634f;
  int b = blockIdx.x;          // 256 = 16 heads x 16 qb
  int h = b & 15, qi = b >> 4; // qb = 16 + qi
  int p0 = (h * 32 + qi * 2);
  int tid = threadIdx.x;
  int row = tid >> 2, seg = (tid & 3) * 32;
  float m1 = ms[p0 * 128 + row], s1 = ms[p0 * 128 + 64 + row];
  float m2 = ms[(p0 + 1) * 128 + row], s2 = ms[(p0 + 1) * 128 + 64 + row];
  float M = fmaxf(m1, m2);
  float w1 = exp2f((m1 - M) * L2E), w2 = exp2f((m2 - M) * L2E);
  float inv = 1.0f / (s1 * w1 + s2 * w2);
  const float* O1 = Opart + (size_t)p0 * 8192 + row * 128 + seg;
  const float* O2 = O1 + 8192;
  h16_t* dst = ctx + (size_t)((16 + qi) * 64 + row) * DM + h * HDIM + seg;
#pragma unroll
  for (int j = 0; j < 32; j += 4) {
    float4 a = *reinterpret_cast<const float4*>(O1 + j);
    float4 c2 = *reinterpret_cast<const float4*>(O2 + j);
    dst[j]     = (h16_t)((a.x * w1 + c2.x * w2) * inv);
    dst[j + 1] = (h16_t)((a.y * w1 + c2.y * w2) * inv);
    dst[j + 2] = (h16_t)((a.z * w1 + c2.z * w2) * inv);
    dst[j + 3] = (h16_t)((a.w * w1 + c2.w * w2) * inv);
  }
}

extern "C" void kernel_launch(void* const* d_in, const int* in_sizes, int n_in,
                              void* d_out, int out_size, void* d_ws, size_t ws_size,
                              hipStream_t stream) {
  const float* hs   = (const float*)d_in[0];
  const float* wqkv = (const float*)d_in[1];
  const float* bqkv = (const float*)d_in[2];
  const float* wo   = (const float*)d_in[3];
  const float* bo   = (const float*)d_in[4];
  float* out = (float*)d_out;

  char* ws = (char*)d_ws;
  const size_t MB = 1u << 20;
  h16_t* h_hi    = (h16_t*)(ws + 0 * MB);    // 8 MB  (reused as ctx16 later)
  h16_t* h_lo    = (h16_t*)(ws + 8 * MB);    // 8 MB
  h16_t* qkvT_hi = (h16_t*)(ws + 16 * MB);   // 24 MB [6144][2048]
  h16_t* qkvT_lo = (h16_t*)(ws + 40 * MB);   // 16 MB [4096][2048]
  h16_t* woT     = (h16_t*)(ws + 56 * MB);   // 8 MB  [2048][2048]
  h16_t* qkv_hi  = (h16_t*)(ws + 64 * MB);   // 24 MB [2048][6144]
  h16_t* qkv_lo  = (h16_t*)(ws + 88 * MB);   // 16 MB [2048][4096]
  float2* ctab   = (float2*)(ws + 104 * MB); // 1 MB  [2048][64]
  h16_t* vt      = (h16_t*)(ws + 105 * MB);  // 8 MB  [2048 vc][2048 s]
  // attn partials reuse the weight-transpose region (consumed before attn):
  float* Opart   = (float*)(ws + 16 * MB);   // 16 MB [512][64][128] fp32
  float* msbuf   = (float*)(ws + 32 * MB);   // 256 KB [512][2][64] fp32
  h16_t* ctx16   = h_hi;

  cvt_split<<<(SEQ * DM / 4 + 255) / 256, 256, 0, stream>>>(hs, h_hi, h_lo, SEQ * DM / 4);
  transpose_split<<<dim3(QKVW / 32, DM / 32), dim3(32, 8), 0, stream>>>(
      wqkv, qkvT_hi, qkvT_lo, DM, QKVW, 4096);
  transpose_split<<<dim3(DM / 32, DM / 32), dim3(32, 8), 0, stream>>>(
      wo, woT, nullptr, DM, DM, 0);
  ctab_kernel<<<(SEQ * 64) / 256, 256, 0, stream>>>(ctab);

  // q,k columns: split 3-product GEMM, writes hi+lo
  gemm_qk<<<dim3(32, 16), 256, 0, stream>>>(
      h_hi, h_lo, qkvT_hi, qkvT_lo, bqkv, qkv_hi, qkv_lo);
  // v columns: plain GEMM, hi only
  gemm_v<<<dim3(16, 16), 256, 0, stream>>>(h_hi, qkvT_hi, bqkv, qkv_hi);

  vtrans_kernel<<<dim3(DM / 32, SEQ / 32), dim3(32, 8), 0, stream>>>(qkv_hi, vt);
  rope_kernel<<<(SEQ * 2 * NHEAD * 64) / 256, 256, 0, stream>>>(qkv_hi, qkv_lo, ctab);

  attn_kernel<<<768, 256, 0, stream>>>(qkv_hi, qkv_lo, vt, ctx16, Opart, msbuf);
  attn_reduce<<<256, 256, 0, stream>>>(Opart, msbuf, ctx16);

  gemm_oproj<<<dim3(DM / 128, SEQ / 128), 256, 0, stream>>>(ctx16, woT, bo, out);
}

// Round 8
// 280.837 us; speedup vs baseline: 1.0985x; 1.0551x over previous
//
#include <hip/hip_runtime.h>

typedef _Float16 h16_t;
typedef _Float16 half8 __attribute__((ext_vector_type(8)));
typedef _Float16 half4v __attribute__((ext_vector_type(4)));
typedef float f32x4 __attribute__((ext_vector_type(4)));

#define SEQ 2048
#define DM 2048
#define NHEAD 16
#define HDIM 128
#define QKVW 6144
#define QKW 4096

#define GLOAD_LDS(g, l)                                                   \
  __builtin_amdgcn_global_load_lds(                                       \
      (const __attribute__((address_space(1))) void*)(g),                 \
      (__attribute__((address_space(3))) void*)(l), 16, 0, 0)

#define VMCNT(n) asm volatile("s_waitcnt vmcnt(" #n ")" ::: "memory")

// ---------------- fp32 -> (hi,lo) fp16 split ----------------
__global__ void cvt_split(const float* __restrict__ src, h16_t* __restrict__ hi,
                          h16_t* __restrict__ lo, int n4) {
  int i = blockIdx.x * blockDim.x + threadIdx.x;
  if (i < n4) {
    float4 v = reinterpret_cast<const float4*>(src)[i];
    half4v h, l;
    float x;
    x = v.x; h[0] = (h16_t)x; l[0] = (h16_t)(x - (float)h[0]);
    x = v.y; h[1] = (h16_t)x; l[1] = (h16_t)(x - (float)h[1]);
    x = v.z; h[2] = (h16_t)x; l[2] = (h16_t)(x - (float)h[2]);
    x = v.w; h[3] = (h16_t)x; l[3] = (h16_t)(x - (float)h[3]);
    reinterpret_cast<half4v*>(hi)[i] = h;
    reinterpret_cast<half4v*>(lo)[i] = l;
  }
}

// ---------------- fp32 W[K][N] -> fp16 Wt[N][K] hi (+ lo for n < Nlo) -------
__global__ void transpose_split(const float* __restrict__ W, h16_t* __restrict__ Wt_hi,
                                h16_t* __restrict__ Wt_lo, int K, int N, int Nlo) {
  __shared__ float tile[32][33];
  int n0 = blockIdx.x * 32, k0 = blockIdx.y * 32;
  int tx = threadIdx.x, ty = threadIdx.y;  // 32 x 8
#pragma unroll
  for (int j = 0; j < 4; ++j)
    tile[ty + 8 * j][tx] = W[(size_t)(k0 + ty + 8 * j) * N + n0 + tx];
  __syncthreads();
  bool do_lo = (Wt_lo != nullptr) && (n0 < Nlo);
#pragma unroll
  for (int j = 0; j < 4; ++j) {
    float v = tile[tx][ty + 8 * j];
    h16_t hv = (h16_t)v;
    size_t off = (size_t)(n0 + ty + 8 * j) * K + k0 + tx;
    Wt_hi[off] = hv;
    if (do_lo) Wt_lo[off] = (h16_t)(v - (float)hv);
  }
}

// ---------------- cos/sin table [SEQ][64] fp32 ----------------
__global__ void ctab_kernel(float2* __restrict__ tab) {
  int idx = blockIdx.x * blockDim.x + threadIdx.x;  // 2048*64
  int s = idx >> 6, i = idx & 63;
  float freq = 1.0f / powf(10000.0f, (float)(2 * i) / 128.0f);
  float ang = (float)s * freq;
  float sn, cs;
  sincosf(ang, &sn, &cs);
  tab[idx] = make_float2(cs, sn);
}

// ---------------- GEMM body: C[M][N] = A[M][K]*Bt[N][K]^T + bias -----------
// 128x128 tile, BK=32, 4 waves (2x2). R5 schedule (verified 104us):
//   stage(next) | ds_reads | MFMA (setprio) | VMCNT0 | syncthreads.
// SPLIT: 3-product Markidis. OUT: 0 = fp16 hi, 1 = fp16 hi+lo, 2 = fp32.
// ROPE: rotate output pairs in-register (tile spans one head) + hi/lo split.
// BROW: bias indexed by output row instead of column.
template <int SPLIT, int OUT, int ROPE, int BROW>
__device__ __forceinline__ void gemm_body(
    char* smem,
    const h16_t* __restrict__ Ahi, const h16_t* __restrict__ Alo,
    const h16_t* __restrict__ Bhi, const h16_t* __restrict__ Blo,
    const float* __restrict__ bias, void* __restrict__ Cout,
    h16_t* __restrict__ Clo, int brow, int bcol, int ldc, int K, int ldlo,
    int tid, const float2* __restrict__ tab) {
  constexpr int BUF = SPLIT ? 32768 : 16384;
  const int w = tid >> 6, lane = tid & 63, c = lane & 15, g = lane >> 4;
  const int wr = (w >> 1) * 64, wc = (w & 1) * 64;

  f32x4 acc[4][4] = {};

  // stage K-step k0 into buffer bufi (linear dest, inverse-swizzled source)
  auto stage = [&](int bufi, int k0) {
    char* buf = smem + bufi * BUF;
#pragma unroll
    for (int it = 0; it < 2; ++it) {
      int B = it * 256 + tid;
      int row = B >> 2;
      int c8 = (B & 3) ^ ((row >> 1) & 3);
      int loff = it * 4096 + w * 1024;
      GLOAD_LDS(Ahi + (size_t)(brow + row) * K + k0 + c8 * 8, buf + loff);
      GLOAD_LDS(Bhi + (size_t)(bcol + row) * K + k0 + c8 * 8, buf + 8192 + loff);
      if (SPLIT) {
        GLOAD_LDS(Alo + (size_t)(brow + row) * K + k0 + c8 * 8, buf + 16384 + loff);
        GLOAD_LDS(Blo + (size_t)(bcol + row) * K + k0 + c8 * 8, buf + 24576 + loff);
      }
    }
  };

  int cur = 0;
  stage(0, 0);
  VMCNT(0);
  __syncthreads();

#pragma unroll 1
  for (int k0 = 0; k0 < K; k0 += 32) {
    if (k0 + 32 < K) stage(cur ^ 1, k0 + 32);
    const char* bufc = smem + cur * BUF;
    half8 afh[4], bfh[4], afl[4], bfl[4];
#pragma unroll
    for (int f = 0; f < 4; ++f) {
      int rowa = wr + f * 16 + c;
      int offa = rowa * 64 + ((g ^ ((rowa >> 1) & 3)) * 16);
      int rowb = wc + f * 16 + c;
      int offb = rowb * 64 + ((g ^ ((rowb >> 1) & 3)) * 16);
      afh[f] = *reinterpret_cast<const half8*>(bufc + offa);
      bfh[f] = *reinterpret_cast<const half8*>(bufc + 8192 + offb);
      if (SPLIT) {
        afl[f] = *reinterpret_cast<const half8*>(bufc + 16384 + offa);
        bfl[f] = *reinterpret_cast<const half8*>(bufc + 24576 + offb);
      }
    }
    __builtin_amdgcn_s_setprio(1);
#pragma unroll
    for (int fm = 0; fm < 4; ++fm)
#pragma unroll
      for (int fn = 0; fn < 4; ++fn) {
        acc[fm][fn] = __builtin_amdgcn_mfma_f32_16x16x32_f16(afh[fm], bfh[fn], acc[fm][fn], 0, 0, 0);
        if (SPLIT) {
          acc[fm][fn] = __builtin_amdgcn_mfma_f32_16x16x32_f16(afh[fm], bfl[fn], acc[fm][fn], 0, 0, 0);
          acc[fm][fn] = __builtin_amdgcn_mfma_f32_16x16x32_f16(afl[fm], bfh[fn], acc[fm][fn], 0, 0, 0);
        }
      }
    __builtin_amdgcn_s_setprio(0);
    VMCNT(0);
    __syncthreads();
    cur ^= 1;
  }

  const float fac = (ROPE && bcol < 2048) ? 11.31370849898476f : 1.0f;
#pragma unroll
  for (int fm = 0; fm < 4; ++fm)
#pragma unroll
    for (int fn = 0; fn < 4; ++fn) {
      int col = bcol + wc + fn * 16 + c;
      float bv = BROW ? 0.f : bias[col];
#pragma unroll
      for (int r = 0; r < 4; ++r) {
        int row = brow + wr + fm * 16 + 4 * g + r;
        float v = acc[fm][fn][r] + (BROW ? bias[row] : bv);
        if (ROPE) {
          // pair (2i,2i+1) sits on adjacent lanes (c even/odd)
          float pv = __shfl_xor(v, 1);
          float2 cc = tab[row * 64 + ((col & 127) >> 1)];
          float y = (col & 1) ? (v * cc.x + pv * cc.y) * fac
                              : (v * cc.x - pv * cc.y) * fac;
          h16_t hv = (h16_t)y;
          ((h16_t*)Cout)[(size_t)row * ldc + col] = hv;
          Clo[(size_t)row * ldlo + col] = (h16_t)(y - (float)hv);
        } else if (OUT == 2) {
          ((float*)Cout)[(size_t)row * ldc + col] = v;
        } else {
          h16_t hv = (h16_t)v;
          ((h16_t*)Cout)[(size_t)row * ldc + col] = hv;
          if (OUT == 1) Clo[(size_t)row * ldlo + col] = (h16_t)(v - (float)hv);
        }
      }
    }
}

// ---------------- q,k columns: split 3-product GEMM + fused RoPE ------------
__global__ __launch_bounds__(256) void gemm_qk(
    const h16_t* __restrict__ h_hi, const h16_t* __restrict__ h_lo,
    const h16_t* __restrict__ qkvT_hi, const h16_t* __restrict__ qkvT_lo,
    const float* __restrict__ bqkv, h16_t* __restrict__ qk_hi,
    h16_t* __restrict__ qk_lo, const float2* __restrict__ tab) {
  __shared__ __align__(16) char smem[65536];
  gemm_body<1, 1, 1, 0>(smem, h_hi, h_lo, qkvT_hi, qkvT_lo, bqkv, qk_hi, qk_lo,
                        blockIdx.y * 128, blockIdx.x * 128, QKW, DM, QKW,
                        threadIdx.x, tab);
}

// ---------------- v columns -> Vt[vc][s] directly (operands swapped) --------
__global__ __launch_bounds__(256) void gemm_v(
    const h16_t* __restrict__ wvT_hi, const h16_t* __restrict__ h_hi,
    const float* __restrict__ bias_v, h16_t* __restrict__ vt) {
  __shared__ __align__(16) char smem[32768];
  gemm_body<0, 0, 0, 1>(smem, wvT_hi, nullptr, h_hi, nullptr, bias_v, vt,
                        nullptr, blockIdx.y * 128, blockIdx.x * 128, SEQ, DM, 0,
                        threadIdx.x, nullptr);
}

// ---------------- out-projection GEMM (fp32 out) ----------------
__global__ __launch_bounds__(256) void gemm_oproj(
    const h16_t* __restrict__ A, const h16_t* __restrict__ Bt,
    const float* __restrict__ bias, float* __restrict__ Cout) {
  __shared__ __align__(16) char smem[32768];
  gemm_body<0, 2, 0, 0>(smem, A, nullptr, Bt, nullptr, bias, Cout, nullptr,
                        blockIdx.y * 128, blockIdx.x * 128, DM, DM, 0,
                        threadIdx.x, nullptr);
}

// ---------------- causal flash attention, split-K + counted-vmcnt ----------
// 768 blocks: h = p&15 (XCD-pinned), cq = p>>4:
//   cq<16 : qb=16+cq, keys [0,1024)            -> partial chunk 0
//   cq<32 : qb=47-cq, keys [1024,(qb+1)*64)    -> partial chunk 1
//   else  : qb=47-cq (15..0), all keys         -> direct ctx write
// 3-buffer pipeline, ONE raw s_barrier per tile, counted vmcnt(6): stage(t)
// issued 2 tiles ahead of use -> L2 latency hidden (no vmcnt(0) drain).
__global__ __launch_bounds__(256) void attn_kernel(const h16_t* __restrict__ qhi,
                                                   const h16_t* __restrict__ qlo,
                                                   const h16_t* __restrict__ vt,
                                                   h16_t* __restrict__ ctx,
                                                   float* __restrict__ Opart,
                                                   float* __restrict__ ms) {
  __shared__ __align__(16) char smem[3 * 24576];
  const int tid = threadIdx.x, w = tid >> 6, lane = tid & 63, c = lane & 15, g = lane >> 4;
  const int p = blockIdx.x;
  const int h = p & 15;
  const int cq = p >> 4;
  int qb, t0, nt, pidx;
  if (cq < 16)      { qb = 16 + cq; t0 = 0;  nt = 32;          pidx = h * 32 + cq * 2; }
  else if (cq < 32) { qb = 47 - cq; t0 = 32; nt = 2 * qb - 30; pidx = h * 32 + (qb - 16) * 2 + 1; }
  else              { qb = 47 - cq; t0 = 0;  nt = 2 * qb + 2;  pidx = -1; }

  const h16_t* Kph = qhi + 2048 + h * HDIM;
  const h16_t* Kpl = qlo + 2048 + h * HDIM;
  const h16_t* Vth = vt + (size_t)h * HDIM * SEQ;
  const float L2E = 1.4426950408889634f;

  const int q0 = qb * 64;
  const int qw = q0 + w * 16;

  // stage one KVBLK=32 tile (Khi, Klo row-major swizzled; Vt [128 d][32 key])
  auto stage = [&](int bufi, int t) {
    char* buf = smem + bufi * 24576;
    const int k0 = t * 32;
#pragma unroll
    for (int it = 0; it < 2; ++it) {
      int B = it * 256 + tid;
      int loff = it * 4096 + w * 1024;
      int row = B >> 4;                       // key row 0..31
      int c16 = (B & 15) ^ (row & 7);
      GLOAD_LDS(Kph + (size_t)(k0 + row) * QKW + c16 * 8, buf + loff);
      GLOAD_LDS(Kpl + (size_t)(k0 + row) * QKW + c16 * 8, buf + 8192 + loff);
      int rv = B >> 2;                        // d row 0..127
      int c4 = (B & 3) ^ ((rv >> 1) & 3);
      GLOAD_LDS(Vth + (size_t)rv * SEQ + k0 + c4 * 8, buf + 16384 + loff);
    }
  };

  half8 qfh[4], qfl[4];
#pragma unroll
  for (int kc = 0; kc < 4; ++kc) {
    qfh[kc] = *reinterpret_cast<const half8*>(qhi + (size_t)(qw + c) * QKW + h * HDIM + kc * 32 + g * 8);
    qfl[kc] = *reinterpret_cast<const half8*>(qlo + (size_t)(qw + c) * QKW + h * HDIM + kc * 32 + g * 8);
  }

  f32x4 oacc[8] = {};
  float m_run = -3.0e38f, s_run = 0.f;

  stage(0, t0);
  if (nt > 1) stage(1, t0 + 1);

#pragma unroll 1
  for (int i = 0; i < nt; ++i) {
    // wait own stage(i) loads complete (6 loads of stage(i+1) may remain),
    // then raw barrier (NO compiler vmcnt(0) drain), then pin ordering.
    if (i + 1 < nt) { VMCNT(6); } else { VMCNT(0); }
    __builtin_amdgcn_s_barrier();
    __builtin_amdgcn_sched_barrier(0);
    if (i + 2 < nt) stage((i + 2) % 3, t0 + i + 2);

    const int k0 = (t0 + i) * 32;
    const char* buf = smem + (i % 3) * 24576;
    const char* bufV = buf + 16384;

    // S^T = K * Q, 3-product split (32 keys x 16 q per wave)
    f32x4 st[2] = {};
    __builtin_amdgcn_s_setprio(1);
#pragma unroll
    for (int kc = 0; kc < 4; ++kc)
#pragma unroll
      for (int fm = 0; fm < 2; ++fm) {
        int row = fm * 16 + c;
        int so = row * 256 + (((4 * kc + g) ^ (row & 7)) * 16);
        half8 kfh = *reinterpret_cast<const half8*>(buf + so);
        half8 kfl = *reinterpret_cast<const half8*>(buf + 8192 + so);
        st[fm] = __builtin_amdgcn_mfma_f32_16x16x32_f16(kfh, qfh[kc], st[fm], 0, 0, 0);
        st[fm] = __builtin_amdgcn_mfma_f32_16x16x32_f16(kfh, qfl[kc], st[fm], 0, 0, 0);
        st[fm] = __builtin_amdgcn_mfma_f32_16x16x32_f16(kfl, qfh[kc], st[fm], 0, 0, 0);
      }
    __builtin_amdgcn_s_setprio(0);

    // causal mask + online softmax (defer-max, THR=8; scale pre-folded into q)
    float p_[2][4];
    float tmax = -3.0e38f;
    const int qg = qw + c;
#pragma unroll
    for (int fm = 0; fm < 2; ++fm)
#pragma unroll
      for (int r = 0; r < 4; ++r) {
        float sf = st[fm][r];
        int key = k0 + fm * 16 + 4 * g + r;
        sf = (key > qg) ? -3.0e38f : sf;
        p_[fm][r] = sf;
        tmax = fmaxf(tmax, sf);
      }
    tmax = fmaxf(tmax, __shfl_xor(tmax, 16));
    tmax = fmaxf(tmax, __shfl_xor(tmax, 32));
    if (!__all(tmax - m_run <= 8.0f)) {
      float m_new = fmaxf(m_run, tmax);
      float alpha = exp2f((m_run - m_new) * L2E);
      float ar[4];
#pragma unroll
      for (int r = 0; r < 4; ++r) ar[r] = __shfl(alpha, 4 * g + r);
#pragma unroll
      for (int tt = 0; tt < 8; ++tt)
#pragma unroll
        for (int r = 0; r < 4; ++r) oacc[tt][r] *= ar[r];
      s_run *= alpha;
      m_run = m_new;
    }
    float rs = 0.f;
#pragma unroll
    for (int fm = 0; fm < 2; ++fm)
#pragma unroll
      for (int r = 0; r < 4; ++r) {
        float e = exp2f((p_[fm][r] - m_run) * L2E);
        p_[fm][r] = e;
        rs += e;
      }
    rs += __shfl_xor(rs, 16);
    rs += __shfl_xor(rs, 32);
    s_run += rs;

    // pack P fragment: slot i <-> key 16*(i>>2) + 4g + (i&3)  (per-lane, free)
    half8 ap;
#pragma unroll
    for (int j = 0; j < 8; ++j) ap[j] = (h16_t)p_[j >> 2][j & 3];

    // PV: B-frag = two swizzled b64 reads of Vt (keys 4g..4g+3, 16+4g..16+4g+3)
    __builtin_amdgcn_s_setprio(1);
#pragma unroll
    for (int tt = 0; tt < 8; ++tt) {
      int row = 16 * tt + c;
      int sw = (row >> 1) & 3;
      int b1 = (g >> 1), b2 = 2 + (g >> 1);
      int a1 = row * 64 + (((b1 ^ sw)) * 16) + 8 * (g & 1);
      int a2 = row * 64 + (((b2 ^ sw)) * 16) + 8 * (g & 1);
      union { half8 v8; half4v v4[2]; } u;
      u.v4[0] = *reinterpret_cast<const half4v*>(bufV + a1);
      u.v4[1] = *reinterpret_cast<const half4v*>(bufV + a2);
      oacc[tt] = __builtin_amdgcn_mfma_f32_16x16x32_f16(ap, u.v8, oacc[tt], 0, 0, 0);
    }
    __builtin_amdgcn_s_setprio(0);
  }

  if (pidx >= 0) {
    // partial: store fp32 O, m, s (consistent w.r.t. m_run reference point)
    float* Od = Opart + (size_t)pidx * 8192;
#pragma unroll
    for (int tt = 0; tt < 8; ++tt)
#pragma unroll
      for (int r = 0; r < 4; ++r)
        Od[(w * 16 + 4 * g + r) * 128 + tt * 16 + c] = oacc[tt][r];
    if (lane < 16) {
      ms[pidx * 128 + w * 16 + c] = m_run;
      ms[pidx * 128 + 64 + w * 16 + c] = s_run;
    }
  } else {
    float sr[4];
#pragma unroll
    for (int r = 0; r < 4; ++r) sr[r] = __shfl(s_run, 4 * g + r);
#pragma unroll
    for (int tt = 0; tt < 8; ++tt)
#pragma unroll
      for (int r = 0; r < 4; ++r) {
        float v = oacc[tt][r] / sr[r];
        ctx[(size_t)(qw + 4 * g + r) * DM + h * HDIM + tt * 16 + c] = (h16_t)v;
      }
  }
}

// ---------------- merge the 2-chunk partials (qb >= 16) ----------------
__global__ void attn_reduce(const float* __restrict__ Opart, const float* __restrict__ ms,
                            h16_t* __restrict__ ctx) {
  const float L2E = 1.4426950408889634f;
  int b = blockIdx.x;          // 256 = 16 heads x 16 qb
  int h = b & 15, qi = b >> 4; // qb = 16 + qi
  int p0 = (h * 32 + qi * 2);
  int tid = threadIdx.x;
  int row = tid >> 2, seg = (tid & 3) * 32;
  float m1 = ms[p0 * 128 + row], s1 = ms[p0 * 128 + 64 + row];
  float m2 = ms[(p0 + 1) * 128 + row], s2 = ms[(p0 + 1) * 128 + 64 + row];
  float M = fmaxf(m1, m2);
  float w1 = exp2f((m1 - M) * L2E), w2 = exp2f((m2 - M) * L2E);
  float inv = 1.0f / (s1 * w1 + s2 * w2);
  const float* O1 = Opart + (size_t)p0 * 8192 + row * 128 + seg;
  const float* O2 = O1 + 8192;
  h16_t* dst = ctx + (size_t)((16 + qi) * 64 + row) * DM + h * HDIM + seg;
#pragma unroll
  for (int j = 0; j < 32; j += 4) {
    float4 a = *reinterpret_cast<const float4*>(O1 + j);
    float4 c2 = *reinterpret_cast<const float4*>(O2 + j);
    dst[j]     = (h16_t)((a.x * w1 + c2.x * w2) * inv);
    dst[j + 1] = (h16_t)((a.y * w1 + c2.y * w2) * inv);
    dst[j + 2] = (h16_t)((a.z * w1 + c2.z * w2) * inv);
    dst[j + 3] = (h16_t)((a.w * w1 + c2.w * w2) * inv);
  }
}

extern "C" void kernel_launch(void* const* d_in, const int* in_sizes, int n_in,
                              void* d_out, int out_size, void* d_ws, size_t ws_size,
                              hipStream_t stream) {
  const float* hs   = (const float*)d_in[0];
  const float* wqkv = (const float*)d_in[1];
  const float* bqkv = (const float*)d_in[2];
  const float* wo   = (const float*)d_in[3];
  const float* bo   = (const float*)d_in[4];
  float* out = (float*)d_out;

  char* ws = (char*)d_ws;
  const size_t MB = 1u << 20;
  h16_t* h_hi    = (h16_t*)(ws + 0 * MB);    // 8 MB  (reused as ctx16 later)
  h16_t* h_lo    = (h16_t*)(ws + 8 * MB);    // 8 MB
  h16_t* qkvT_hi = (h16_t*)(ws + 16 * MB);   // 24 MB [6144][2048]
  h16_t* qkvT_lo = (h16_t*)(ws + 40 * MB);   // 16 MB [4096][2048]
  h16_t* woT     = (h16_t*)(ws + 56 * MB);   // 8 MB  [2048][2048]
  h16_t* qk_hi   = (h16_t*)(ws + 64 * MB);   // 16 MB [2048][4096]
  h16_t* qk_lo   = (h16_t*)(ws + 88 * MB);   // 16 MB [2048][4096]
  float2* ctab   = (float2*)(ws + 104 * MB); // 1 MB  [2048][64]
  h16_t* vt      = (h16_t*)(ws + 105 * MB);  // 8 MB  [2048 vc][2048 s]
  // attn partials reuse the weight-transpose region (consumed before attn):
  float* Opart   = (float*)(ws + 16 * MB);   // 16 MB [512][64][128] fp32
  float* msbuf   = (float*)(ws + 32 * MB);   // 256 KB [512][2][64] fp32
  h16_t* ctx16   = h_hi;

  cvt_split<<<(SEQ * DM / 4 + 255) / 256, 256, 0, stream>>>(hs, h_hi, h_lo, SEQ * DM / 4);
  transpose_split<<<dim3(QKVW / 32, DM / 32), dim3(32, 8), 0, stream>>>(
      wqkv, qkvT_hi, qkvT_lo, DM, QKVW, 4096);
  transpose_split<<<dim3(DM / 32, DM / 32), dim3(32, 8), 0, stream>>>(
      wo, woT, nullptr, DM, DM, 0);
  ctab_kernel<<<(SEQ * 64) / 256, 256, 0, stream>>>(ctab);

  // q,k columns: split 3-product GEMM + fused RoPE (exact fp32 rotate+resplit)
  gemm_qk<<<dim3(32, 16), 256, 0, stream>>>(
      h_hi, h_lo, qkvT_hi, qkvT_lo, bqkv, qk_hi, qk_lo, ctab);
  // v columns: Vt[vc][s] = WvT * h^T + bias_v (direct transposed output)
  gemm_v<<<dim3(16, 16), 256, 0, stream>>>(
      qkvT_hi + (size_t)4096 * DM, h_hi, bqkv + 4096, vt);

  attn_kernel<<<768, 256, 0, stream>>>(qk_hi, qk_lo, vt, ctx16, Opart, msbuf);
  attn_reduce<<<256, 256, 0, stream>>>(Opart, msbuf, ctx16);

  gemm_oproj<<<dim3(DM / 128, SEQ / 128), 256, 0, stream>>>(ctx16, woT, bo, out);
}

// Round 9
// 271.845 us; speedup vs baseline: 1.1348x; 1.0331x over previous
//
#include <hip/hip_runtime.h>

typedef _Float16 h16_t;
typedef _Float16 half8 __attribute__((ext_vector_type(8)));
typedef _Float16 half4v __attribute__((ext_vector_type(4)));
typedef float f32x4 __attribute__((ext_vector_type(4)));

#define SEQ 2048
#define DM 2048
#define NHEAD 16
#define HDIM 128
#define QKVW 6144
#define QKW 4096

#define GLOAD_LDS(g, l)                                                   \
  __builtin_amdgcn_global_load_lds(                                       \
      (const __attribute__((address_space(1))) void*)(g),                 \
      (__attribute__((address_space(3))) void*)(l), 16, 0, 0)

#define VMCNT(n) asm volatile("s_waitcnt vmcnt(" #n ")" ::: "memory")

// ---------------- fp32 -> (hi,lo) fp16 split ----------------
__global__ void cvt_split(const float* __restrict__ src, h16_t* __restrict__ hi,
                          h16_t* __restrict__ lo, int n4) {
  int i = blockIdx.x * blockDim.x + threadIdx.x;
  if (i < n4) {
    float4 v = reinterpret_cast<const float4*>(src)[i];
    half4v h, l;
    float x;
    x = v.x; h[0] = (h16_t)x; l[0] = (h16_t)(x - (float)h[0]);
    x = v.y; h[1] = (h16_t)x; l[1] = (h16_t)(x - (float)h[1]);
    x = v.z; h[2] = (h16_t)x; l[2] = (h16_t)(x - (float)h[2]);
    x = v.w; h[3] = (h16_t)x; l[3] = (h16_t)(x - (float)h[3]);
    reinterpret_cast<half4v*>(hi)[i] = h;
    reinterpret_cast<half4v*>(lo)[i] = l;
  }
}

// ------- fp32 W[K][N] -> fp16 Wt[N][K] hi (+ lo for n < Nlo), vectorized ----
// 64x64 tile, float4 loads, half8 stores. LDS +1-pad; write-phase reads are
// <=2-way bank aliased (free).
__global__ void transpose_split(const float* __restrict__ W, h16_t* __restrict__ Wt_hi,
                                h16_t* __restrict__ Wt_lo, int K, int N, int Nlo) {
  __shared__ float tile[64][65];
  int n0 = blockIdx.x * 64, k0 = blockIdx.y * 64;
  int t = threadIdx.x;  // 256
  int row = t >> 4, c4 = t & 15;
#pragma unroll
  for (int j = 0; j < 4; ++j) {
    float4 v = *reinterpret_cast<const float4*>(
        &W[(size_t)(k0 + j * 16 + row) * N + n0 + c4 * 4]);
    tile[j * 16 + row][c4 * 4 + 0] = v.x;
    tile[j * 16 + row][c4 * 4 + 1] = v.y;
    tile[j * 16 + row][c4 * 4 + 2] = v.z;
    tile[j * 16 + row][c4 * 4 + 3] = v.w;
  }
  __syncthreads();
  bool do_lo = (Wt_lo != nullptr) && (n0 < Nlo);
#pragma unroll
  for (int jj = 0; jj < 2; ++jj) {
    int idx = jj * 256 + t;
    int n = idx >> 3, kc = idx & 7;
    half8 hv, lv;
#pragma unroll
    for (int e = 0; e < 8; ++e) {
      float x = tile[kc * 8 + e][n];
      h16_t h = (h16_t)x;
      hv[e] = h;
      lv[e] = (h16_t)(x - (float)h);
    }
    size_t off = (size_t)(n0 + n) * K + k0 + kc * 8;
    *reinterpret_cast<half8*>(&Wt_hi[off]) = hv;
    if (do_lo) *reinterpret_cast<half8*>(&Wt_lo[off]) = lv;
  }
}

// ---------------- cos/sin table [SEQ][64] fp32 ----------------
__global__ void ctab_kernel(float2* __restrict__ tab) {
  int idx = blockIdx.x * blockDim.x + threadIdx.x;  // 2048*64
  int s = idx >> 6, i = idx & 63;
  float freq = 1.0f / powf(10000.0f, (float)(2 * i) / 128.0f);
  float ang = (float)s * freq;
  float sn, cs;
  sincosf(ang, &sn, &cs);
  tab[idx] = make_float2(cs, sn);
}

// ---------------- GEMM body: C[M][N] = A[M][K]*Bt[N][K]^T + bias -----------
// 128x128 tile, BK=32, 4 waves (2x2). R5 schedule (verified 104-106us):
//   stage(next) | ds_reads | MFMA (setprio) | VMCNT0 | syncthreads.
// SPLIT: 3-product Markidis. OUT: 0 = fp16 hi, 1 = fp16 hi+lo, 2 = fp32.
// ROPE: rotate output pairs in-register (tile spans one head) + hi/lo split.
// BROW: bias indexed by output row instead of column.
template <int SPLIT, int OUT, int ROPE, int BROW>
__device__ __forceinline__ void gemm_body(
    char* smem,
    const h16_t* __restrict__ Ahi, const h16_t* __restrict__ Alo,
    const h16_t* __restrict__ Bhi, const h16_t* __restrict__ Blo,
    const float* __restrict__ bias, void* __restrict__ Cout,
    h16_t* __restrict__ Clo, int brow, int bcol, int ldc, int K, int ldlo,
    int tid, const float2* __restrict__ tab) {
  constexpr int BUF = SPLIT ? 32768 : 16384;
  const int w = tid >> 6, lane = tid & 63, c = lane & 15, g = lane >> 4;
  const int wr = (w >> 1) * 64, wc = (w & 1) * 64;

  f32x4 acc[4][4] = {};

  // stage K-step k0 into buffer bufi (linear dest, inverse-swizzled source)
  auto stage = [&](int bufi, int k0) {
    char* buf = smem + bufi * BUF;
#pragma unroll
    for (int it = 0; it < 2; ++it) {
      int B = it * 256 + tid;
      int row = B >> 2;
      int c8 = (B & 3) ^ ((row >> 1) & 3);
      int loff = it * 4096 + w * 1024;
      GLOAD_LDS(Ahi + (size_t)(brow + row) * K + k0 + c8 * 8, buf + loff);
      GLOAD_LDS(Bhi + (size_t)(bcol + row) * K + k0 + c8 * 8, buf + 8192 + loff);
      if (SPLIT) {
        GLOAD_LDS(Alo + (size_t)(brow + row) * K + k0 + c8 * 8, buf + 16384 + loff);
        GLOAD_LDS(Blo + (size_t)(bcol + row) * K + k0 + c8 * 8, buf + 24576 + loff);
      }
    }
  };

  int cur = 0;
  stage(0, 0);
  VMCNT(0);
  __syncthreads();

#pragma unroll 1
  for (int k0 = 0; k0 < K; k0 += 32) {
    if (k0 + 32 < K) stage(cur ^ 1, k0 + 32);
    const char* bufc = smem + cur * BUF;
    half8 afh[4], bfh[4], afl[4], bfl[4];
#pragma unroll
    for (int f = 0; f < 4; ++f) {
      int rowa = wr + f * 16 + c;
      int offa = rowa * 64 + ((g ^ ((rowa >> 1) & 3)) * 16);
      int rowb = wc + f * 16 + c;
      int offb = rowb * 64 + ((g ^ ((rowb >> 1) & 3)) * 16);
      afh[f] = *reinterpret_cast<const half8*>(bufc + offa);
      bfh[f] = *reinterpret_cast<const half8*>(bufc + 8192 + offb);
      if (SPLIT) {
        afl[f] = *reinterpret_cast<const half8*>(bufc + 16384 + offa);
        bfl[f] = *reinterpret_cast<const half8*>(bufc + 24576 + offb);
      }
    }
    __builtin_amdgcn_s_setprio(1);
#pragma unroll
    for (int fm = 0; fm < 4; ++fm)
#pragma unroll
      for (int fn = 0; fn < 4; ++fn) {
        acc[fm][fn] = __builtin_amdgcn_mfma_f32_16x16x32_f16(afh[fm], bfh[fn], acc[fm][fn], 0, 0, 0);
        if (SPLIT) {
          acc[fm][fn] = __builtin_amdgcn_mfma_f32_16x16x32_f16(afh[fm], bfl[fn], acc[fm][fn], 0, 0, 0);
          acc[fm][fn] = __builtin_amdgcn_mfma_f32_16x16x32_f16(afl[fm], bfh[fn], acc[fm][fn], 0, 0, 0);
        }
      }
    __builtin_amdgcn_s_setprio(0);
    VMCNT(0);
    __syncthreads();
    cur ^= 1;
  }

  const float fac = (ROPE && bcol < 2048) ? 11.31370849898476f : 1.0f;
#pragma unroll
  for (int fm = 0; fm < 4; ++fm)
#pragma unroll
    for (int fn = 0; fn < 4; ++fn) {
      int col = bcol + wc + fn * 16 + c;
      float bv = BROW ? 0.f : bias[col];
#pragma unroll
      for (int r = 0; r < 4; ++r) {
        int row = brow + wr + fm * 16 + 4 * g + r;
        float v = acc[fm][fn][r] + (BROW ? bias[row] : bv);
        if (ROPE) {
          // pair (2i,2i+1) sits on adjacent lanes (c even/odd)
          float pv = __shfl_xor(v, 1);
          float2 cc = tab[row * 64 + ((col & 127) >> 1)];
          float y = (col & 1) ? (v * cc.x + pv * cc.y) * fac
                              : (v * cc.x - pv * cc.y) * fac;
          h16_t hv = (h16_t)y;
          ((h16_t*)Cout)[(size_t)row * ldc + col] = hv;
          Clo[(size_t)row * ldlo + col] = (h16_t)(y - (float)hv);
        } else if (OUT == 2) {
          ((float*)Cout)[(size_t)row * ldc + col] = v;
        } else {
          h16_t hv = (h16_t)v;
          ((h16_t*)Cout)[(size_t)row * ldc + col] = hv;
          if (OUT == 1) Clo[(size_t)row * ldlo + col] = (h16_t)(v - (float)hv);
        }
      }
    }
}

// ------- merged QKV GEMM, v blocks FIRST (backfill), qk blocks after --------
// p < 256 : Vt[vc][s] = WvT * h^T + bias_v (plain, transposed output)
// p >= 256: q,k cols, split 3-product + fused RoPE, x-major as standalone.
__global__ __launch_bounds__(256) void gemm_qkv(
    const h16_t* __restrict__ h_hi, const h16_t* __restrict__ h_lo,
    const h16_t* __restrict__ qkvT_hi, const h16_t* __restrict__ qkvT_lo,
    const float* __restrict__ bqkv, h16_t* __restrict__ qk_hi,
    h16_t* __restrict__ qk_lo, h16_t* __restrict__ vt,
    const float2* __restrict__ tab) {
  __shared__ __align__(16) char smem[65536];
  const int p = blockIdx.x, tid = threadIdx.x;
  if (p < 256) {
    gemm_body<0, 0, 0, 1>(smem, qkvT_hi + (size_t)4096 * DM, nullptr, h_hi,
                          nullptr, bqkv + 4096, vt, nullptr,
                          (p >> 4) * 128, (p & 15) * 128, SEQ, DM, 0, tid,
                          nullptr);
  } else {
    const int q = p - 256;
    gemm_body<1, 1, 1, 0>(smem, h_hi, h_lo, qkvT_hi, qkvT_lo, bqkv, qk_hi,
                          qk_lo, (q >> 5) * 128, (q & 31) * 128, QKW, DM, QKW,
                          tid, tab);
  }
}

// ---------------- out-projection GEMM (fp32 out) ----------------
__global__ __launch_bounds__(256) void gemm_oproj(
    const h16_t* __restrict__ A, const h16_t* __restrict__ Bt,
    const float* __restrict__ bias, float* __restrict__ Cout) {
  __shared__ __align__(16) char smem[32768];
  gemm_body<0, 2, 0, 0>(smem, A, nullptr, Bt, nullptr, bias, Cout, nullptr,
                        blockIdx.y * 128, blockIdx.x * 128, DM, DM, 0,
                        threadIdx.x, nullptr);
}

// ---------------- causal flash attention, split-K + counted-vmcnt ----------
// 768 blocks: h = p&15 (XCD-pinned), cq = p>>4:
//   cq<16 : qb=16+cq, keys [0,1024)            -> partial chunk 0
//   cq<32 : qb=47-cq, keys [1024,(qb+1)*64)    -> partial chunk 1
//   else  : qb=47-cq (15..0), all keys         -> direct ctx write
// 3-buffer pipeline, ONE raw s_barrier per tile, counted vmcnt(6): stage(t)
// issued 2 tiles ahead of use -> L2 latency hidden (no vmcnt(0) drain).
__global__ __launch_bounds__(256) void attn_kernel(const h16_t* __restrict__ qhi,
                                                   const h16_t* __restrict__ qlo,
                                                   const h16_t* __restrict__ vt,
                                                   h16_t* __restrict__ ctx,
                                                   float* __restrict__ Opart,
                                                   float* __restrict__ ms) {
  __shared__ __align__(16) char smem[3 * 24576];
  const int tid = threadIdx.x, w = tid >> 6, lane = tid & 63, c = lane & 15, g = lane >> 4;
  const int p = blockIdx.x;
  const int h = p & 15;
  const int cq = p >> 4;
  int qb, t0, nt, pidx;
  if (cq < 16)      { qb = 16 + cq; t0 = 0;  nt = 32;          pidx = h * 32 + cq * 2; }
  else if (cq < 32) { qb = 47 - cq; t0 = 32; nt = 2 * qb - 30; pidx = h * 32 + (qb - 16) * 2 + 1; }
  else              { qb = 47 - cq; t0 = 0;  nt = 2 * qb + 2;  pidx = -1; }

  const h16_t* Kph = qhi + 2048 + h * HDIM;
  const h16_t* Kpl = qlo + 2048 + h * HDIM;
  const h16_t* Vth = vt + (size_t)h * HDIM * SEQ;
  const float L2E = 1.4426950408889634f;

  const int q0 = qb * 64;
  const int qw = q0 + w * 16;

  // stage one KVBLK=32 tile (Khi, Klo row-major swizzled; Vt [128 d][32 key])
  auto stage = [&](int bufi, int t) {
    char* buf = smem + bufi * 24576;
    const int k0 = t * 32;
#pragma unroll
    for (int it = 0; it < 2; ++it) {
      int B = it * 256 + tid;
      int loff = it * 4096 + w * 1024;
      int row = B >> 4;                       // key row 0..31
      int c16 = (B & 15) ^ (row & 7);
      GLOAD_LDS(Kph + (size_t)(k0 + row) * QKW + c16 * 8, buf + loff);
      GLOAD_LDS(Kpl + (size_t)(k0 + row) * QKW + c16 * 8, buf + 8192 + loff);
      int rv = B >> 2;                        // d row 0..127
      int c4 = (B & 3) ^ ((rv >> 1) & 3);
      GLOAD_LDS(Vth + (size_t)rv * SEQ + k0 + c4 * 8, buf + 16384 + loff);
    }
  };

  half8 qfh[4], qfl[4];
#pragma unroll
  for (int kc = 0; kc < 4; ++kc) {
    qfh[kc] = *reinterpret_cast<const half8*>(qhi + (size_t)(qw + c) * QKW + h * HDIM + kc * 32 + g * 8);
    qfl[kc] = *reinterpret_cast<const half8*>(qlo + (size_t)(qw + c) * QKW + h * HDIM + kc * 32 + g * 8);
  }

  f32x4 oacc[8] = {};
  float m_run = -3.0e38f, s_run = 0.f;

  stage(0, t0);
  if (nt > 1) stage(1, t0 + 1);

#pragma unroll 1
  for (int i = 0; i < nt; ++i) {
    // wait own stage(i) loads complete (6 loads of stage(i+1) may remain),
    // then raw barrier (NO compiler vmcnt(0) drain), then pin ordering.
    if (i + 1 < nt) { VMCNT(6); } else { VMCNT(0); }
    __builtin_amdgcn_s_barrier();
    __builtin_amdgcn_sched_barrier(0);
    if (i + 2 < nt) stage((i + 2) % 3, t0 + i + 2);

    const int k0 = (t0 + i) * 32;
    const char* buf = smem + (i % 3) * 24576;
    const char* bufV = buf + 16384;

    // S^T = K * Q, 3-product split (32 keys x 16 q per wave)
    f32x4 st[2] = {};
    __builtin_amdgcn_s_setprio(1);
#pragma unroll
    for (int kc = 0; kc < 4; ++kc)
#pragma unroll
      for (int fm = 0; fm < 2; ++fm) {
        int row = fm * 16 + c;
        int so = row * 256 + (((4 * kc + g) ^ (row & 7)) * 16);
        half8 kfh = *reinterpret_cast<const half8*>(buf + so);
        half8 kfl = *reinterpret_cast<const half8*>(buf + 8192 + so);
        st[fm] = __builtin_amdgcn_mfma_f32_16x16x32_f16(kfh, qfh[kc], st[fm], 0, 0, 0);
        st[fm] = __builtin_amdgcn_mfma_f32_16x16x32_f16(kfh, qfl[kc], st[fm], 0, 0, 0);
        st[fm] = __builtin_amdgcn_mfma_f32_16x16x32_f16(kfl, qfh[kc], st[fm], 0, 0, 0);
      }
    __builtin_amdgcn_s_setprio(0);

    // causal mask + online softmax (defer-max, THR=8; scale pre-folded into q)
    float p_[2][4];
    float tmax = -3.0e38f;
    const int qg = qw + c;
#pragma unroll
    for (int fm = 0; fm < 2; ++fm)
#pragma unroll
      for (int r = 0; r < 4; ++r) {
        float sf = st[fm][r];
        int key = k0 + fm * 16 + 4 * g + r;
        sf = (key > qg) ? -3.0e38f : sf;
        p_[fm][r] = sf;
        tmax = fmaxf(tmax, sf);
      }
    tmax = fmaxf(tmax, __shfl_xor(tmax, 16));
    tmax = fmaxf(tmax, __shfl_xor(tmax, 32));
    if (!__all(tmax - m_run <= 8.0f)) {
      float m_new = fmaxf(m_run, tmax);
      float alpha = exp2f((m_run - m_new) * L2E);
      float ar[4];
#pragma unroll
      for (int r = 0; r < 4; ++r) ar[r] = __shfl(alpha, 4 * g + r);
#pragma unroll
      for (int tt = 0; tt < 8; ++tt)
#pragma unroll
        for (int r = 0; r < 4; ++r) oacc[tt][r] *= ar[r];
      s_run *= alpha;
      m_run = m_new;
    }
    float rs = 0.f;
#pragma unroll
    for (int fm = 0; fm < 2; ++fm)
#pragma unroll
      for (int r = 0; r < 4; ++r) {
        float e = exp2f((p_[fm][r] - m_run) * L2E);
        p_[fm][r] = e;
        rs += e;
      }
    rs += __shfl_xor(rs, 16);
    rs += __shfl_xor(rs, 32);
    s_run += rs;

    // pack P fragment: slot i <-> key 16*(i>>2) + 4g + (i&3)  (per-lane, free)
    half8 ap;
#pragma unroll
    for (int j = 0; j < 8; ++j) ap[j] = (h16_t)p_[j >> 2][j & 3];

    // PV: B-frag = two swizzled b64 reads of Vt (keys 4g..4g+3, 16+4g..16+4g+3)
    __builtin_amdgcn_s_setprio(1);
#pragma unroll
    for (int tt = 0; tt < 8; ++tt) {
      int row = 16 * tt + c;
      int sw = (row >> 1) & 3;
      int b1 = (g >> 1), b2 = 2 + (g >> 1);
      int a1 = row * 64 + (((b1 ^ sw)) * 16) + 8 * (g & 1);
      int a2 = row * 64 + (((b2 ^ sw)) * 16) + 8 * (g & 1);
      union { half8 v8; half4v v4[2]; } u;
      u.v4[0] = *reinterpret_cast<const half4v*>(bufV + a1);
      u.v4[1] = *reinterpret_cast<const half4v*>(bufV + a2);
      oacc[tt] = __builtin_amdgcn_mfma_f32_16x16x32_f16(ap, u.v8, oacc[tt], 0, 0, 0);
    }
    __builtin_amdgcn_s_setprio(0);
  }

  if (pidx >= 0) {
    // partial: store fp32 O, m, s (consistent w.r.t. m_run reference point)
    float* Od = Opart + (size_t)pidx * 8192;
#pragma unroll
    for (int tt = 0; tt < 8; ++tt)
#pragma unroll
      for (int r = 0; r < 4; ++r)
        Od[(w * 16 + 4 * g + r) * 128 + tt * 16 + c] = oacc[tt][r];
    if (lane < 16) {
      ms[pidx * 128 + w * 16 + c] = m_run;
      ms[pidx * 128 + 64 + w * 16 + c] = s_run;
    }
  } else {
    float sr[4];
#pragma unroll
    for (int r = 0; r < 4; ++r) sr[r] = __shfl(s_run, 4 * g + r);
#pragma unroll
    for (int tt = 0; tt < 8; ++tt)
#pragma unroll
      for (int r = 0; r < 4; ++r) {
        float v = oacc[tt][r] / sr[r];
        ctx[(size_t)(qw + 4 * g + r) * DM + h * HDIM + tt * 16 + c] = (h16_t)v;
      }
  }
}

// ---------------- merge the 2-chunk partials (qb >= 16) ----------------
__global__ void attn_reduce(const float* __restrict__ Opart, const float* __restrict__ ms,
                            h16_t* __restrict__ ctx) {
  const float L2E = 1.4426950408889634f;
  int b = blockIdx.x;          // 256 = 16 heads x 16 qb
  int h = b & 15, qi = b >> 4; // qb = 16 + qi
  int p0 = (h * 32 + qi * 2);
  int tid = threadIdx.x;
  int row = tid >> 2, seg = (tid & 3) * 32;
  float m1 = ms[p0 * 128 + row], s1 = ms[p0 * 128 + 64 + row];
  float m2 = ms[(p0 + 1) * 128 + row], s2 = ms[(p0 + 1) * 128 + 64 + row];
  float M = fmaxf(m1, m2);
  float w1 = exp2f((m1 - M) * L2E), w2 = exp2f((m2 - M) * L2E);
  float inv = 1.0f / (s1 * w1 + s2 * w2);
  const float* O1 = Opart + (size_t)p0 * 8192 + row * 128 + seg;
  const float* O2 = O1 + 8192;
  h16_t* dst = ctx + (size_t)((16 + qi) * 64 + row) * DM + h * HDIM + seg;
#pragma unroll
  for (int j = 0; j < 32; j += 4) {
    float4 a = *reinterpret_cast<const float4*>(O1 + j);
    float4 c2 = *reinterpret_cast<const float4*>(O2 + j);
    dst[j]     = (h16_t)((a.x * w1 + c2.x * w2) * inv);
    dst[j + 1] = (h16_t)((a.y * w1 + c2.y * w2) * inv);
    dst[j + 2] = (h16_t)((a.z * w1 + c2.z * w2) * inv);
    dst[j + 3] = (h16_t)((a.w * w1 + c2.w * w2) * inv);
  }
}

extern "C" void kernel_launch(void* const* d_in, const int* in_sizes, int n_in,
                              void* d_out, int out_size, void* d_ws, size_t ws_size,
                              hipStream_t stream) {
  const float* hs   = (const float*)d_in[0];
  const float* wqkv = (const float*)d_in[1];
  const float* bqkv = (const float*)d_in[2];
  const float* wo   = (const float*)d_in[3];
  const float* bo   = (const float*)d_in[4];
  float* out = (float*)d_out;

  char* ws = (char*)d_ws;
  const size_t MB = 1u << 20;
  h16_t* h_hi    = (h16_t*)(ws + 0 * MB);    // 8 MB  (reused as ctx16 later)
  h16_t* h_lo    = (h16_t*)(ws + 8 * MB);    // 8 MB
  h16_t* qkvT_hi = (h16_t*)(ws + 16 * MB);   // 24 MB [6144][2048]
  h16_t* qkvT_lo = (h16_t*)(ws + 40 * MB);   // 16 MB [4096][2048]
  h16_t* woT     = (h16_t*)(ws + 56 * MB);   // 8 MB  [2048][2048]
  h16_t* qk_hi   = (h16_t*)(ws + 64 * MB);   // 16 MB [2048][4096]
  h16_t* qk_lo   = (h16_t*)(ws + 88 * MB);   // 16 MB [2048][4096]
  float2* ctab   = (float2*)(ws + 104 * MB); // 1 MB  [2048][64]
  h16_t* vt      = (h16_t*)(ws + 105 * MB);  // 8 MB  [2048 vc][2048 s]
  // attn partials reuse the weight-transpose region (consumed before attn):
  float* Opart   = (float*)(ws + 16 * MB);   // 16 MB [512][64][128] fp32
  float* msbuf   = (float*)(ws + 32 * MB);   // 256 KB [512][2][64] fp32
  h16_t* ctx16   = h_hi;

  cvt_split<<<(SEQ * DM / 4 + 255) / 256, 256, 0, stream>>>(hs, h_hi, h_lo, SEQ * DM / 4);
  transpose_split<<<dim3(QKVW / 64, DM / 64), 256, 0, stream>>>(
      wqkv, qkvT_hi, qkvT_lo, DM, QKVW, 4096);
  transpose_split<<<dim3(DM / 64, DM / 64), 256, 0, stream>>>(
      wo, woT, nullptr, DM, DM, 0);
  ctab_kernel<<<(SEQ * 64) / 256, 256, 0, stream>>>(ctab);

  // merged QKV: p<256 -> Vt blocks (short, dispatch first); p>=256 -> split
  // q,k blocks with fused RoPE (x-major, same relative order as standalone)
  gemm_qkv<<<768, 256, 0, stream>>>(
      h_hi, h_lo, qkvT_hi, qkvT_lo, bqkv, qk_hi, qk_lo, vt, ctab);

  attn_kernel<<<768, 256, 0, stream>>>(qk_hi, qk_lo, vt, ctx16, Opart, msbuf);
  attn_reduce<<<256, 256, 0, stream>>>(Opart, msbuf, ctx16);

  gemm_oproj<<<dim3(DM / 128, SEQ / 128), 256, 0, stream>>>(ctx16, woT, bo, out);
}

// Round 10
// 251.954 us; speedup vs baseline: 1.2244x; 1.0789x over previous
//
#include <hip/hip_runtime.h>

typedef _Float16 h16_t;
typedef _Float16 half8 __attribute__((ext_vector_type(8)));
typedef _Float16 half4v __attribute__((ext_vector_type(4)));
typedef float f32x4 __attribute__((ext_vector_type(4)));

#define SEQ 2048
#define DM 2048
#define NHEAD 16
#define HDIM 128
#define QKVW 6144
#define QKW 4096

#define GLOAD_LDS(g, l)                                                   \
  __builtin_amdgcn_global_load_lds(                                       \
      (const __attribute__((address_space(1))) void*)(g),                 \
      (__attribute__((address_space(3))) void*)(l), 16, 0, 0)

#define VMCNT(n) asm volatile("s_waitcnt vmcnt(" #n ")" ::: "memory")

// ---------------- fp32 -> (hi,lo) fp16 split ----------------
__global__ void cvt_split(const float* __restrict__ src, h16_t* __restrict__ hi,
                          h16_t* __restrict__ lo, int n4) {
  int i = blockIdx.x * blockDim.x + threadIdx.x;
  if (i < n4) {
    float4 v = reinterpret_cast<const float4*>(src)[i];
    half4v h, l;
    float x;
    x = v.x; h[0] = (h16_t)x; l[0] = (h16_t)(x - (float)h[0]);
    x = v.y; h[1] = (h16_t)x; l[1] = (h16_t)(x - (float)h[1]);
    x = v.z; h[2] = (h16_t)x; l[2] = (h16_t)(x - (float)h[2]);
    x = v.w; h[3] = (h16_t)x; l[3] = (h16_t)(x - (float)h[3]);
    reinterpret_cast<half4v*>(hi)[i] = h;
    reinterpret_cast<half4v*>(lo)[i] = l;
  }
}

// ------- fp32 W[K][N] -> fp16 Wt[N][K] (hi only), vectorized ----------------
__global__ void transpose_f16(const float* __restrict__ W, h16_t* __restrict__ Wt,
                              int K, int N) {
  __shared__ float tile[64][65];
  int n0 = blockIdx.x * 64, k0 = blockIdx.y * 64;
  int t = threadIdx.x;  // 256
  int row = t >> 4, c4 = t & 15;
#pragma unroll
  for (int j = 0; j < 4; ++j) {
    float4 v = *reinterpret_cast<const float4*>(
        &W[(size_t)(k0 + j * 16 + row) * N + n0 + c4 * 4]);
    tile[j * 16 + row][c4 * 4 + 0] = v.x;
    tile[j * 16 + row][c4 * 4 + 1] = v.y;
    tile[j * 16 + row][c4 * 4 + 2] = v.z;
    tile[j * 16 + row][c4 * 4 + 3] = v.w;
  }
  __syncthreads();
#pragma unroll
  for (int jj = 0; jj < 2; ++jj) {
    int idx = jj * 256 + t;
    int n = idx >> 3, kc = idx & 7;
    half8 hv;
#pragma unroll
    for (int e = 0; e < 8; ++e) hv[e] = (h16_t)tile[kc * 8 + e][n];
    *reinterpret_cast<half8*>(&Wt[(size_t)(n0 + n) * K + k0 + kc * 8]) = hv;
  }
}

// ---------------- cos/sin table [SEQ][64] fp32 ----------------
__global__ void ctab_kernel(float2* __restrict__ tab) {
  int idx = blockIdx.x * blockDim.x + threadIdx.x;  // 2048*64
  int s = idx >> 6, i = idx & 63;
  float freq = 1.0f / powf(10000.0f, (float)(2 * i) / 128.0f);
  float ang = (float)s * freq;
  float sn, cs;
  sincosf(ang, &sn, &cs);
  tab[idx] = make_float2(cs, sn);
}

// ---------------- GEMM body: C[M][N] = A[M][K]*Bt[N][K]^T + bias -----------
// 128x128 tile, BK=32, 4 waves (2x2). R5 schedule (verified):
//   stage(next) | ds_reads | MFMA (setprio) | VMCNT0 | syncthreads.
// ASPLIT: 2-product (Ahi+Alo)*Bhi — removes A-rounding error, keeps W error.
// OUT: 0 = fp16 hi, 1 = fp16 hi+lo, 2 = fp32.
// ROPE: rotate output pairs in-register (tile spans one head) + hi/lo split.
// BROW: bias indexed by output row instead of column.
template <int ASPLIT, int OUT, int ROPE, int BROW>
__device__ __forceinline__ void gemm_body(
    char* smem,
    const h16_t* __restrict__ Ahi, const h16_t* __restrict__ Alo,
    const h16_t* __restrict__ Bhi,
    const float* __restrict__ bias, void* __restrict__ Cout,
    h16_t* __restrict__ Clo, int brow, int bcol, int ldc, int K, int ldlo,
    int tid, const float2* __restrict__ tab) {
  constexpr int BUF = ASPLIT ? 24576 : 16384;
  const int w = tid >> 6, lane = tid & 63, c = lane & 15, g = lane >> 4;
  const int wr = (w >> 1) * 64, wc = (w & 1) * 64;

  f32x4 acc[4][4] = {};

  // stage K-step k0 into buffer bufi (linear dest, inverse-swizzled source)
  auto stage = [&](int bufi, int k0) {
    char* buf = smem + bufi * BUF;
#pragma unroll
    for (int it = 0; it < 2; ++it) {
      int B = it * 256 + tid;
      int row = B >> 2;
      int c8 = (B & 3) ^ ((row >> 1) & 3);
      int loff = it * 4096 + w * 1024;
      GLOAD_LDS(Ahi + (size_t)(brow + row) * K + k0 + c8 * 8, buf + loff);
      GLOAD_LDS(Bhi + (size_t)(bcol + row) * K + k0 + c8 * 8, buf + 8192 + loff);
      if (ASPLIT)
        GLOAD_LDS(Alo + (size_t)(brow + row) * K + k0 + c8 * 8, buf + 16384 + loff);
    }
  };

  int cur = 0;
  stage(0, 0);
  VMCNT(0);
  __syncthreads();

#pragma unroll 1
  for (int k0 = 0; k0 < K; k0 += 32) {
    if (k0 + 32 < K) stage(cur ^ 1, k0 + 32);
    const char* bufc = smem + cur * BUF;
    half8 afh[4], bfh[4], afl[4];
#pragma unroll
    for (int f = 0; f < 4; ++f) {
      int rowa = wr + f * 16 + c;
      int offa = rowa * 64 + ((g ^ ((rowa >> 1) & 3)) * 16);
      int rowb = wc + f * 16 + c;
      int offb = rowb * 64 + ((g ^ ((rowb >> 1) & 3)) * 16);
      afh[f] = *reinterpret_cast<const half8*>(bufc + offa);
      bfh[f] = *reinterpret_cast<const half8*>(bufc + 8192 + offb);
      if (ASPLIT) afl[f] = *reinterpret_cast<const half8*>(bufc + 16384 + offa);
    }
    __builtin_amdgcn_s_setprio(1);
#pragma unroll
    for (int fm = 0; fm < 4; ++fm)
#pragma unroll
      for (int fn = 0; fn < 4; ++fn) {
        acc[fm][fn] = __builtin_amdgcn_mfma_f32_16x16x32_f16(afh[fm], bfh[fn], acc[fm][fn], 0, 0, 0);
        if (ASPLIT)
          acc[fm][fn] = __builtin_amdgcn_mfma_f32_16x16x32_f16(afl[fm], bfh[fn], acc[fm][fn], 0, 0, 0);
      }
    __builtin_amdgcn_s_setprio(0);
    VMCNT(0);
    __syncthreads();
    cur ^= 1;
  }

  const float fac = (ROPE && bcol < 2048) ? 11.31370849898476f : 1.0f;
#pragma unroll
  for (int fm = 0; fm < 4; ++fm)
#pragma unroll
    for (int fn = 0; fn < 4; ++fn) {
      int col = bcol + wc + fn * 16 + c;
      float bv = BROW ? 0.f : bias[col];
#pragma unroll
      for (int r = 0; r < 4; ++r) {
        int row = brow + wr + fm * 16 + 4 * g + r;
        float v = acc[fm][fn][r] + (BROW ? bias[row] : bv);
        if (ROPE) {
          // pair (2i,2i+1) sits on adjacent lanes (c even/odd)
          float pv = __shfl_xor(v, 1);
          float2 cc = tab[row * 64 + ((col & 127) >> 1)];
          float y = (col & 1) ? (v * cc.x + pv * cc.y) * fac
                              : (v * cc.x - pv * cc.y) * fac;
          h16_t hv = (h16_t)y;
          ((h16_t*)Cout)[(size_t)row * ldc + col] = hv;
          Clo[(size_t)row * ldlo + col] = (h16_t)(y - (float)hv);
        } else if (OUT == 2) {
          ((float*)Cout)[(size_t)row * ldc + col] = v;
        } else {
          h16_t hv = (h16_t)v;
          ((h16_t*)Cout)[(size_t)row * ldc + col] = hv;
          if (OUT == 1) Clo[(size_t)row * ldlo + col] = (h16_t)(v - (float)hv);
        }
      }
    }
}

// ---------------- q,k columns: 2-product A-split GEMM + fused RoPE ----------
__global__ __launch_bounds__(256) void gemm_qk(
    const h16_t* __restrict__ h_hi, const h16_t* __restrict__ h_lo,
    const h16_t* __restrict__ qkvT_hi, const float* __restrict__ bqkv,
    h16_t* __restrict__ qk_hi, h16_t* __restrict__ qk_lo,
    const float2* __restrict__ tab) {
  __shared__ __align__(16) char smem[49152];
  gemm_body<1, 1, 1, 0>(smem, h_hi, h_lo, qkvT_hi, bqkv, qk_hi, qk_lo,
                        blockIdx.y * 128, blockIdx.x * 128, QKW, DM, QKW,
                        threadIdx.x, tab);
}

// ---------------- v columns -> Vt[vc][s] directly (operands swapped) --------
__global__ __launch_bounds__(256) void gemm_v(
    const h16_t* __restrict__ wvT_hi, const h16_t* __restrict__ h_hi,
    const float* __restrict__ bias_v, h16_t* __restrict__ vt) {
  __shared__ __align__(16) char smem[32768];
  gemm_body<0, 0, 0, 1>(smem, wvT_hi, nullptr, h_hi, bias_v, vt,
                        nullptr, blockIdx.y * 128, blockIdx.x * 128, SEQ, DM, 0,
                        threadIdx.x, nullptr);
}

// ---------------- out-projection GEMM (fp32 out) ----------------
__global__ __launch_bounds__(256) void gemm_oproj(
    const h16_t* __restrict__ A, const h16_t* __restrict__ Bt,
    const float* __restrict__ bias, float* __restrict__ Cout) {
  __shared__ __align__(16) char smem[32768];
  gemm_body<0, 2, 0, 0>(smem, A, nullptr, Bt, bias, Cout, nullptr,
                        blockIdx.y * 128, blockIdx.x * 128, DM, DM, 0,
                        threadIdx.x, nullptr);
}

// ---------------- causal flash attention, split-K + counted-vmcnt ----------
// 768 blocks: h = p&15 (XCD-pinned), cq = p>>4:
//   cq<16 : qb=16+cq, keys [0,1024)            -> partial chunk 0
//   cq<32 : qb=47-cq, keys [1024,(qb+1)*64)    -> partial chunk 1
//   else  : qb=47-cq (15..0), all keys         -> direct ctx write
// 3-buffer pipeline, ONE raw s_barrier per tile, counted vmcnt(6): stage(t)
// issued 2 tiles ahead of use -> L2 latency hidden (no vmcnt(0) drain).
__global__ __launch_bounds__(256) void attn_kernel(const h16_t* __restrict__ qhi,
                                                   const h16_t* __restrict__ qlo,
                                                   const h16_t* __restrict__ vt,
                                                   h16_t* __restrict__ ctx,
                                                   float* __restrict__ Opart,
                                                   float* __restrict__ ms) {
  __shared__ __align__(16) char smem[3 * 24576];
  const int tid = threadIdx.x, w = tid >> 6, lane = tid & 63, c = lane & 15, g = lane >> 4;
  const int p = blockIdx.x;
  const int h = p & 15;
  const int cq = p >> 4;
  int qb, t0, nt, pidx;
  if (cq < 16)      { qb = 16 + cq; t0 = 0;  nt = 32;          pidx = h * 32 + cq * 2; }
  else if (cq < 32) { qb = 47 - cq; t0 = 32; nt = 2 * qb - 30; pidx = h * 32 + (qb - 16) * 2 + 1; }
  else              { qb = 47 - cq; t0 = 0;  nt = 2 * qb + 2;  pidx = -1; }

  const h16_t* Kph = qhi + 2048 + h * HDIM;
  const h16_t* Kpl = qlo + 2048 + h * HDIM;
  const h16_t* Vth = vt + (size_t)h * HDIM * SEQ;
  const float L2E = 1.4426950408889634f;

  const int q0 = qb * 64;
  const int qw = q0 + w * 16;

  // stage one KVBLK=32 tile (Khi, Klo row-major swizzled; Vt [128 d][32 key])
  auto stage = [&](int bufi, int t) {
    char* buf = smem + bufi * 24576;
    const int k0 = t * 32;
#pragma unroll
    for (int it = 0; it < 2; ++it) {
      int B = it * 256 + tid;
      int loff = it * 4096 + w * 1024;
      int row = B >> 4;                       // key row 0..31
      int c16 = (B & 15) ^ (row & 7);
      GLOAD_LDS(Kph + (size_t)(k0 + row) * QKW + c16 * 8, buf + loff);
      GLOAD_LDS(Kpl + (size_t)(k0 + row) * QKW + c16 * 8, buf + 8192 + loff);
      int rv = B >> 2;                        // d row 0..127
      int c4 = (B & 3) ^ ((rv >> 1) & 3);
      GLOAD_LDS(Vth + (size_t)rv * SEQ + k0 + c4 * 8, buf + 16384 + loff);
    }
  };

  half8 qfh[4], qfl[4];
#pragma unroll
  for (int kc = 0; kc < 4; ++kc) {
    qfh[kc] = *reinterpret_cast<const half8*>(qhi + (size_t)(qw + c) * QKW + h * HDIM + kc * 32 + g * 8);
    qfl[kc] = *reinterpret_cast<const half8*>(qlo + (size_t)(qw + c) * QKW + h * HDIM + kc * 32 + g * 8);
  }

  f32x4 oacc[8] = {};
  float m_run = -3.0e38f, s_run = 0.f;

  stage(0, t0);
  if (nt > 1) stage(1, t0 + 1);

#pragma unroll 1
  for (int i = 0; i < nt; ++i) {
    // wait own stage(i) loads complete (6 loads of stage(i+1) may remain),
    // then raw barrier (NO compiler vmcnt(0) drain), then pin ordering.
    if (i + 1 < nt) { VMCNT(6); } else { VMCNT(0); }
    __builtin_amdgcn_s_barrier();
    __builtin_amdgcn_sched_barrier(0);
    if (i + 2 < nt) stage((i + 2) % 3, t0 + i + 2);

    const int k0 = (t0 + i) * 32;
    const char* buf = smem + (i % 3) * 24576;
    const char* bufV = buf + 16384;

    // S^T = K * Q, 3-product split (32 keys x 16 q per wave)
    f32x4 st[2] = {};
    __builtin_amdgcn_s_setprio(1);
#pragma unroll
    for (int kc = 0; kc < 4; ++kc)
#pragma unroll
      for (int fm = 0; fm < 2; ++fm) {
        int row = fm * 16 + c;
        int so = row * 256 + (((4 * kc + g) ^ (row & 7)) * 16);
        half8 kfh = *reinterpret_cast<const half8*>(buf + so);
        half8 kfl = *reinterpret_cast<const half8*>(buf + 8192 + so);
        st[fm] = __builtin_amdgcn_mfma_f32_16x16x32_f16(kfh, qfh[kc], st[fm], 0, 0, 0);
        st[fm] = __builtin_amdgcn_mfma_f32_16x16x32_f16(kfh, qfl[kc], st[fm], 0, 0, 0);
        st[fm] = __builtin_amdgcn_mfma_f32_16x16x32_f16(kfl, qfh[kc], st[fm], 0, 0, 0);
      }
    __builtin_amdgcn_s_setprio(0);

    // causal mask + online softmax (defer-max, THR=8; scale pre-folded into q)
    float p_[2][4];
    float tmax = -3.0e38f;
    const int qg = qw + c;
#pragma unroll
    for (int fm = 0; fm < 2; ++fm)
#pragma unroll
      for (int r = 0; r < 4; ++r) {
        float sf = st[fm][r];
        int key = k0 + fm * 16 + 4 * g + r;
        sf = (key > qg) ? -3.0e38f : sf;
        p_[fm][r] = sf;
        tmax = fmaxf(tmax, sf);
      }
    tmax = fmaxf(tmax, __shfl_xor(tmax, 16));
    tmax = fmaxf(tmax, __shfl_xor(tmax, 32));
    if (!__all(tmax - m_run <= 8.0f)) {
      float m_new = fmaxf(m_run, tmax);
      float alpha = exp2f((m_run - m_new) * L2E);
      float ar[4];
#pragma unroll
      for (int r = 0; r < 4; ++r) ar[r] = __shfl(alpha, 4 * g + r);
#pragma unroll
      for (int tt = 0; tt < 8; ++tt)
#pragma unroll
        for (int r = 0; r < 4; ++r) oacc[tt][r] *= ar[r];
      s_run *= alpha;
      m_run = m_new;
    }
    float rs = 0.f;
#pragma unroll
    for (int fm = 0; fm < 2; ++fm)
#pragma unroll
      for (int r = 0; r < 4; ++r) {
        float e = exp2f((p_[fm][r] - m_run) * L2E);
        p_[fm][r] = e;
        rs += e;
      }
    rs += __shfl_xor(rs, 16);
    rs += __shfl_xor(rs, 32);
    s_run += rs;

    // pack P fragment: slot i <-> key 16*(i>>2) + 4g + (i&3)  (per-lane, free)
    half8 ap;
#pragma unroll
    for (int j = 0; j < 8; ++j) ap[j] = (h16_t)p_[j >> 2][j & 3];

    // PV: B-frag = two swizzled b64 reads of Vt (keys 4g..4g+3, 16+4g..16+4g+3)
    __builtin_amdgcn_s_setprio(1);
#pragma unroll
    for (int tt = 0; tt < 8; ++tt) {
      int row = 16 * tt + c;
      int sw = (row >> 1) & 3;
      int b1 = (g >> 1), b2 = 2 + (g >> 1);
      int a1 = row * 64 + (((b1 ^ sw)) * 16) + 8 * (g & 1);
      int a2 = row * 64 + (((b2 ^ sw)) * 16) + 8 * (g & 1);
      union { half8 v8; half4v v4[2]; } u;
      u.v4[0] = *reinterpret_cast<const half4v*>(bufV + a1);
      u.v4[1] = *reinterpret_cast<const half4v*>(bufV + a2);
      oacc[tt] = __builtin_amdgcn_mfma_f32_16x16x32_f16(ap, u.v8, oacc[tt], 0, 0, 0);
    }
    __builtin_amdgcn_s_setprio(0);
  }

  if (pidx >= 0) {
    // partial: store fp32 O, m, s (consistent w.r.t. m_run reference point)
    float* Od = Opart + (size_t)pidx * 8192;
#pragma unroll
    for (int tt = 0; tt < 8; ++tt)
#pragma unroll
      for (int r = 0; r < 4; ++r)
        Od[(w * 16 + 4 * g + r) * 128 + tt * 16 + c] = oacc[tt][r];
    if (lane < 16) {
      ms[pidx * 128 + w * 16 + c] = m_run;
      ms[pidx * 128 + 64 + w * 16 + c] = s_run;
    }
  } else {
    float sr[4];
#pragma unroll
    for (int r = 0; r < 4; ++r) sr[r] = __shfl(s_run, 4 * g + r);
#pragma unroll
    for (int tt = 0; tt < 8; ++tt)
#pragma unroll
      for (int r = 0; r < 4; ++r) {
        float v = oacc[tt][r] / sr[r];
        ctx[(size_t)(qw + 4 * g + r) * DM + h * HDIM + tt * 16 + c] = (h16_t)v;
      }
  }
}

// ---------------- merge the 2-chunk partials (qb >= 16) ----------------
__global__ void attn_reduce(const float* __restrict__ Opart, const float* __restrict__ ms,
                            h16_t* __restrict__ ctx) {
  const float L2E = 1.4426950408889634f;
  int b = blockIdx.x;          // 256 = 16 heads x 16 qb
  int h = b & 15, qi = b >> 4; // qb = 16 + qi
  int p0 = (h * 32 + qi * 2);
  int tid = threadIdx.x;
  int row = tid >> 2, seg = (tid & 3) * 32;
  float m1 = ms[p0 * 128 + row], s1 = ms[p0 * 128 + 64 + row];
  float m2 = ms[(p0 + 1) * 128 + row], s2 = ms[(p0 + 1) * 128 + 64 + row];
  float M = fmaxf(m1, m2);
  float w1 = exp2f((m1 - M) * L2E), w2 = exp2f((m2 - M) * L2E);
  float inv = 1.0f / (s1 * w1 + s2 * w2);
  const float* O1 = Opart + (size_t)p0 * 8192 + row * 128 + seg;
  const float* O2 = O1 + 8192;
  h16_t* dst = ctx + (size_t)((16 + qi) * 64 + row) * DM + h * HDIM + seg;
#pragma unroll
  for (int j = 0; j < 32; j += 4) {
    float4 a = *reinterpret_cast<const float4*>(O1 + j);
    float4 c2 = *reinterpret_cast<const float4*>(O2 + j);
    dst[j]     = (h16_t)((a.x * w1 + c2.x * w2) * inv);
    dst[j + 1] = (h16_t)((a.y * w1 + c2.y * w2) * inv);
    dst[j + 2] = (h16_t)((a.z * w1 + c2.z * w2) * inv);
    dst[j + 3] = (h16_t)((a.w * w1 + c2.w * w2) * inv);
  }
}

extern "C" void kernel_launch(void* const* d_in, const int* in_sizes, int n_in,
                              void* d_out, int out_size, void* d_ws, size_t ws_size,
                              hipStream_t stream) {
  const float* hs   = (const float*)d_in[0];
  const float* wqkv = (const float*)d_in[1];
  const float* bqkv = (const float*)d_in[2];
  const float* wo   = (const float*)d_in[3];
  const float* bo   = (const float*)d_in[4];
  float* out = (float*)d_out;

  char* ws = (char*)d_ws;
  const size_t MB = 1u << 20;
  h16_t* h_hi    = (h16_t*)(ws + 0 * MB);    // 8 MB  (reused as ctx16 later)
  h16_t* h_lo    = (h16_t*)(ws + 8 * MB);    // 8 MB
  h16_t* qkvT_hi = (h16_t*)(ws + 16 * MB);   // 24 MB [6144][2048]
  h16_t* woT     = (h16_t*)(ws + 56 * MB);   // 8 MB  [2048][2048]
  h16_t* qk_hi   = (h16_t*)(ws + 64 * MB);   // 16 MB [2048][4096]
  h16_t* qk_lo   = (h16_t*)(ws + 88 * MB);   // 16 MB [2048][4096]
  float2* ctab   = (float2*)(ws + 104 * MB); // 1 MB  [2048][64]
  h16_t* vt      = (h16_t*)(ws + 105 * MB);  // 8 MB  [2048 vc][2048 s]
  // attn partials reuse the qkvT region (consumed before attn):
  float* Opart   = (float*)(ws + 16 * MB);   // 16 MB [512][64][128] fp32
  float* msbuf   = (float*)(ws + 32 * MB);   // 256 KB [512][2][64] fp32
  h16_t* ctx16   = h_hi;

  cvt_split<<<(SEQ * DM / 4 + 255) / 256, 256, 0, stream>>>(hs, h_hi, h_lo, SEQ * DM / 4);
  transpose_f16<<<dim3(QKVW / 64, DM / 64), 256, 0, stream>>>(wqkv, qkvT_hi, DM, QKVW);
  transpose_f16<<<dim3(DM / 64, DM / 64), 256, 0, stream>>>(wo, woT, DM, DM);
  ctab_kernel<<<(SEQ * 64) / 256, 256, 0, stream>>>(ctab);

  // q,k columns: 2-product A-split GEMM + fused RoPE (exact fp32 rotate+resplit)
  gemm_qk<<<dim3(32, 16), 256, 0, stream>>>(
      h_hi, h_lo, qkvT_hi, bqkv, qk_hi, qk_lo, ctab);
  // v columns: Vt[vc][s] = WvT * h^T + bias_v (direct transposed output)
  gemm_v<<<dim3(16, 16), 256, 0, stream>>>(
      qkvT_hi + (size_t)4096 * DM, h_hi, bqkv + 4096, vt);

  attn_kernel<<<768, 256, 0, stream>>>(qk_hi, qk_lo, vt, ctx16, Opart, msbuf);
  attn_reduce<<<256, 256, 0, stream>>>(Opart, msbuf, ctx16);

  gemm_oproj<<<dim3(DM / 128, SEQ / 128), 256, 0, stream>>>(ctx16, woT, bo, out);
}